// Round 2
// baseline (10239.201 us; speedup 1.0000x reference)
//
#include <hip/hip_runtime.h>

// ---------------------------------------------------------------------------
// MultiHeadAttention (full-width per-head projections), MI355X gfx950.
// Round 2: same math as round 1 (3-term bf16 hi/lo split for Q/K proj and
// QK^T; fp32 softmax; bf16 V/PV/out-proj) but the launcher is now
// ws_size-adaptive: head-group chunking HG in {12,4,2,1} and full-vs-per-batch
// concat-O buffer, so the workspace footprint ranges 431 MB -> 143 MB.
// Round-1 crash diagnosis: unconditional 431 MB carve from d_ws.
// ---------------------------------------------------------------------------

typedef __attribute__((ext_vector_type(8))) short bf16x8;
typedef __attribute__((ext_vector_type(4))) float fx4;

#define NB 8
#define NS 1024
#define ND 768
#define NH 12
#define NHD 9216  // NH*ND

__device__ __forceinline__ unsigned short f2bf(float x) {
    unsigned int u = __float_as_uint(x);
    u += 0x7fffu + ((u >> 16) & 1u);   // round-to-nearest-even bf16
    return (unsigned short)(u >> 16);
}
__device__ __forceinline__ float bf2f(unsigned short h) {
    return __uint_as_float(((unsigned int)h) << 16);
}

// ---------------- elementwise split: f32 -> bf16 hi + bf16 lo ----------------
__global__ void k_split(const float* __restrict__ in, unsigned short* __restrict__ hi,
                        unsigned short* __restrict__ lo, int n4) {
    int i = blockIdx.x * 256 + threadIdx.x;
    if (i >= n4) return;
    float4 v = ((const float4*)in)[i];
    ushort4 h, l;
    h.x = f2bf(v.x); l.x = f2bf(v.x - bf2f(h.x));
    h.y = f2bf(v.y); l.y = f2bf(v.y - bf2f(h.y));
    h.z = f2bf(v.z); l.z = f2bf(v.z - bf2f(h.z));
    h.w = f2bf(v.w); l.w = f2bf(v.w - bf2f(h.w));
    ((ushort4*)hi)[i] = h;
    ((ushort4*)lo)[i] = l;
}

// ------------- transpose f32 [z][R][C] -> bf16 (hi[,lo]) [z][C][R] -----------
template<bool SPLIT>
__global__ void k_transpose(const float* __restrict__ in, unsigned short* __restrict__ oh,
                            unsigned short* __restrict__ ol, int R, int C) {
    __shared__ float tile[64][65];
    long zo = (long)blockIdx.z * R * C;
    in += zo; oh += zo; if (SPLIT) ol += zo;
    int c0 = blockIdx.x * 64, r0 = blockIdx.y * 64;
    int tc = threadIdx.x & 63, t4 = threadIdx.x >> 6;
    #pragma unroll
    for (int i = 0; i < 16; i++) {
        int r = (i << 2) + t4;
        tile[r][tc] = in[(long)(r0 + r) * C + c0 + tc];
    }
    __syncthreads();
    #pragma unroll
    for (int i = 0; i < 16; i++) {
        int c = (i << 2) + t4;
        float v = tile[tc][c];
        long o = (long)(c0 + c) * R + r0 + tc;
        unsigned short h = f2bf(v);
        oh[o] = h;
        if constexpr (SPLIT) ol[o] = f2bf(v - bf2f(h));
    }
}

// ---------------------------------------------------------------------------
// Generic MFMA GEMM core: C_tile[128x128] = sum_t A_t[128xK] * B_t[KxN-tile]
// A row-major [*, lda] k-contig; B given as BT row-major [n, ldb] k-contig.
// NTERMS==3: Ah*Bh + Ah*Bl + Al*Bh (split-bf16 product).
// Fragment k-order uses one consistent bijection for A and B (layout-proof:
// for 16x16x32 bf16 the (lane,reg)->k map is identical for A and B operands,
// so any k-permutation applied to both cancels).
// C/D layout (HW-verified): col = lane&15, row = (lane>>4)*4 + reg.
// LDS: [128 rows][4 slots of 16B], slot ^= (row>>1)&3 -> conflict-floor.
// ---------------------------------------------------------------------------
template<int NTERMS, class Epi>
__device__ __forceinline__ void gemm_core(
    const unsigned short* __restrict__ Ah, const unsigned short* __restrict__ Al, long lda,
    const unsigned short* __restrict__ Bh, const unsigned short* __restrict__ Bl, long ldb,
    int K, Epi epi)
{
    constexpr int NBUF = (NTERMS == 3) ? 4 : 2;
    __shared__ __align__(16) unsigned short sm[NBUF][4096];

    const int t = threadIdx.x;
    const int lane = t & 63;
    const int wid = t >> 6;
    const int wm = (wid >> 1) << 6;   // wave row offset (0/64)
    const int wn = (wid & 1) << 6;    // wave col offset (0/64)
    const int lr = lane & 15;
    const int lg = lane >> 4;

    // staging: thread t handles row t>>1, 32B at k-offset (t&1)*16
    const int srow = t >> 1;
    const int skq = (t & 1) << 4;
    const int fsw = (srow >> 1) & 3;
    const int d0 = srow * 32 + ((((t & 1) << 1) ^ fsw) << 3);
    const int d1 = srow * 32 + (((((t & 1) << 1) | 1) ^ fsw) << 3);

    fx4 acc[4][4] = {};

    int offA[4], offB[4];
    #pragma unroll
    for (int i = 0; i < 4; i++) {
        int ra = wm + (i << 4) + lr;
        offA[i] = ra * 32 + ((lg ^ ((ra >> 1) & 3)) << 3);
        int rb = wn + (i << 4) + lr;
        offB[i] = rb * 32 + ((lg ^ ((rb >> 1) & 3)) << 3);
    }

    for (int k0 = 0; k0 < K; k0 += 32) {
        __syncthreads();
        {
            const unsigned short* g = Ah + (long)srow * lda + k0 + skq;
            uint4 va0 = *(const uint4*)g;
            uint4 va1 = *(const uint4*)(g + 8);
            g = Bh + (long)srow * ldb + k0 + skq;
            uint4 vb0 = *(const uint4*)g;
            uint4 vb1 = *(const uint4*)(g + 8);
            *(uint4*)&sm[0][d0] = va0;
            *(uint4*)&sm[0][d1] = va1;
            *(uint4*)&sm[1][d0] = vb0;
            *(uint4*)&sm[1][d1] = vb1;
            if constexpr (NTERMS == 3) {
                g = Al + (long)srow * lda + k0 + skq;
                uint4 vc0 = *(const uint4*)g;
                uint4 vc1 = *(const uint4*)(g + 8);
                g = Bl + (long)srow * ldb + k0 + skq;
                uint4 ve0 = *(const uint4*)g;
                uint4 ve1 = *(const uint4*)(g + 8);
                *(uint4*)&sm[2][d0] = vc0;
                *(uint4*)&sm[2][d1] = vc1;
                *(uint4*)&sm[3][d0] = ve0;
                *(uint4*)&sm[3][d1] = ve1;
            }
        }
        __syncthreads();

        bf16x8 fa[4], fb[4], fa2[4], fb2[4];
        #pragma unroll
        for (int i = 0; i < 4; i++) {
            fa[i] = *(const bf16x8*)&sm[0][offA[i]];
            fb[i] = *(const bf16x8*)&sm[1][offB[i]];
        }
        if constexpr (NTERMS == 3) {
            #pragma unroll
            for (int i = 0; i < 4; i++) {
                fa2[i] = *(const bf16x8*)&sm[2][offA[i]];
                fb2[i] = *(const bf16x8*)&sm[3][offB[i]];
            }
        }
        #pragma unroll
        for (int i = 0; i < 4; i++)
            #pragma unroll
            for (int j = 0; j < 4; j++) {
                acc[i][j] = __builtin_amdgcn_mfma_f32_16x16x32_bf16(fa[i], fb[j], acc[i][j], 0, 0, 0);
                if constexpr (NTERMS == 3) {
                    acc[i][j] = __builtin_amdgcn_mfma_f32_16x16x32_bf16(fa[i], fb2[j], acc[i][j], 0, 0, 0);
                    acc[i][j] = __builtin_amdgcn_mfma_f32_16x16x32_bf16(fa2[i], fb[j], acc[i][j], 0, 0, 0);
                }
            }
    }

    #pragma unroll
    for (int i = 0; i < 4; i++)
        #pragma unroll
        for (int j = 0; j < 4; j++)
            #pragma unroll
            for (int r = 0; r < 4; r++)
                epi(wm + (i << 4) + (lg << 2) + r, wn + (j << 4) + lr, acc[i][j][r]);
}

// ------------------------- GEMM wrapper kernels ------------------------------
// h0 = global head offset of this chunk; blockIdx.z = local head index.

// Q/K projection: out[hl][s][e] split bf16 (chunk-local). grid (6, 8, HG)
__global__ __launch_bounds__(256, 2) void k_proj_qk(
    const unsigned short* __restrict__ xh, const unsigned short* __restrict__ xl,
    const unsigned short* __restrict__ WTh, const unsigned short* __restrict__ WTl,
    const float* __restrict__ bias,
    unsigned short* __restrict__ Oh, unsigned short* __restrict__ Ol, int h0)
{
    const int hl = blockIdx.z;
    const int h = h0 + hl;
    const int m0 = blockIdx.y << 7;
    const int n0 = blockIdx.x << 7;
    const unsigned short* Ah = xh + (long)m0 * ND;
    const unsigned short* Al = xl + (long)m0 * ND;
    const unsigned short* Bh = WTh + (long)h * ND * ND + (long)n0 * ND;
    const unsigned short* Bl = WTl + (long)h * ND * ND + (long)n0 * ND;
    unsigned short* oh = Oh + ((long)hl * NS + m0) * ND + n0;
    unsigned short* ol = Ol + ((long)hl * NS + m0) * ND + n0;
    const float* bi = bias + h * ND + n0;
    gemm_core<3>(Ah, Al, ND, Bh, Bl, ND, ND, [=](int r, int c, float v) {
        v += bi[c];
        unsigned short hh = f2bf(v);
        oh[(long)r * ND + c] = hh;
        ol[(long)r * ND + c] = f2bf(v - bf2f(hh));
    });
}

// V projection: writes V^T[hl][e][t] bf16 (chunk-local). grid (6, 8, HG)
__global__ __launch_bounds__(256, 2) void k_proj_v(
    const unsigned short* __restrict__ xh, const unsigned short* __restrict__ WTh,
    const float* __restrict__ bias, unsigned short* __restrict__ VT, int h0)
{
    const int hl = blockIdx.z;
    const int h = h0 + hl;
    const int m0 = blockIdx.y << 7;
    const int n0 = blockIdx.x << 7;
    const unsigned short* Ah = xh + (long)m0 * ND;
    const unsigned short* Bh = WTh + (long)h * ND * ND + (long)n0 * ND;
    unsigned short* vt = VT + (long)hl * ND * NS;
    const float* bi = bias + h * ND + n0;
    gemm_core<1>(Ah, nullptr, ND, Bh, nullptr, ND, ND, [=](int r, int c, float v) {
        v += bi[c];
        vt[(long)(n0 + c) * NS + m0 + r] = f2bf(v);
    });
}

// scores[hl][s][t] fp32 (unscaled), chunk-local. grid (8, 8, HG)
__global__ __launch_bounds__(256, 2) void k_scores(
    const unsigned short* __restrict__ Qh, const unsigned short* __restrict__ Ql,
    const unsigned short* __restrict__ Kh, const unsigned short* __restrict__ Kl,
    float* __restrict__ Sc)
{
    const int z = blockIdx.z;
    const int m0 = blockIdx.y << 7;
    const int n0 = blockIdx.x << 7;
    const unsigned short* Ah = Qh + ((long)z * NS + m0) * ND;
    const unsigned short* Al = Ql + ((long)z * NS + m0) * ND;
    const unsigned short* Bh = Kh + ((long)z * NS + n0) * ND;
    const unsigned short* Bl = Kl + ((long)z * NS + n0) * ND;
    float* out = Sc + ((long)z * NS + m0) * NS + n0;
    gemm_core<3>(Ah, Al, ND, Bh, Bl, ND, ND, [=](int r, int c, float v) {
        out[(long)r * NS + c] = v;
    });
}

// row softmax of 8*score, fp32 in -> bf16 P out. one wave per 1024-row.
__global__ __launch_bounds__(256) void k_softmax(const float* __restrict__ Sc,
                                                 unsigned short* __restrict__ P) {
    int row = blockIdx.x * 4 + (threadIdx.x >> 6);
    int lane = threadIdx.x & 63;
    const float4* src = (const float4*)(Sc + (long)row * NS) + (lane << 2);
    float v[16];
    #pragma unroll
    for (int i = 0; i < 4; i++) {
        float4 a = src[i];
        v[i * 4 + 0] = a.x; v[i * 4 + 1] = a.y; v[i * 4 + 2] = a.z; v[i * 4 + 3] = a.w;
    }
    float m = v[0];
    #pragma unroll
    for (int i = 1; i < 16; i++) m = fmaxf(m, v[i]);
    #pragma unroll
    for (int o = 32; o > 0; o >>= 1) m = fmaxf(m, __shfl_xor(m, o));
    float s = 0.f, p[16];
    #pragma unroll
    for (int i = 0; i < 16; i++) { p[i] = __expf((v[i] - m) * 8.0f); s += p[i]; }
    #pragma unroll
    for (int o = 32; o > 0; o >>= 1) s += __shfl_xor(s, o);
    float inv = 1.0f / s;
    unsigned int w[8];
    #pragma unroll
    for (int i = 0; i < 8; i++) {
        unsigned int u0 = f2bf(p[2 * i] * inv);
        unsigned int u1 = f2bf(p[2 * i + 1] * inv);
        w[i] = u0 | (u1 << 16);
    }
    uint4* dst = (uint4*)(P + (long)row * NS + (lane << 4));
    dst[0] = make_uint4(w[0], w[1], w[2], w[3]);
    dst[1] = make_uint4(w[4], w[5], w[6], w[7]);
}

// O = P @ V into concat layout rows of O2base[row][NHD], cols (h0+z)*768+.
// grid (6, 8, HG)
__global__ __launch_bounds__(256, 2) void k_pv(
    const unsigned short* __restrict__ P, const unsigned short* __restrict__ VT,
    unsigned short* __restrict__ O2base, int h0)
{
    const int z = blockIdx.z;
    const int m0 = blockIdx.y << 7;
    const int n0 = blockIdx.x << 7;
    const unsigned short* Ah = P + ((long)z * NS + m0) * NS;
    const unsigned short* Bh = VT + ((long)z * ND + n0) * NS;
    unsigned short* out = O2base + (long)m0 * NHD + (long)(h0 + z) * ND + n0;
    gemm_core<1>(Ah, nullptr, NS, Bh, nullptr, NS, NS, [=](int r, int c, float v) {
        out[(long)r * NHD + c] = f2bf(v);
    });
}

// out[m0.., n0..] = O2base[m0..][:] @ WpT + bp, fp32. grid (6, rows/128)
__global__ __launch_bounds__(256, 2) void k_out(
    const unsigned short* __restrict__ O2base, const unsigned short* __restrict__ WpT,
    const float* __restrict__ bp, float* __restrict__ outbase)
{
    const int m0 = blockIdx.y << 7;
    const int n0 = blockIdx.x << 7;
    const unsigned short* Ah = O2base + (long)m0 * NHD;
    const unsigned short* Bh = WpT + (long)n0 * NHD;
    float* o = outbase + (long)m0 * ND + n0;
    const float* bi = bp + n0;
    gemm_core<1>(Ah, nullptr, NHD, Bh, nullptr, NHD, NHD, [=](int r, int c, float v) {
        o[(long)r * ND + c] = v + bi[c];
    });
}

// ---------------------------------------------------------------------------

extern "C" void kernel_launch(void* const* d_in, const int* in_sizes, int n_in,
                              void* d_out, int out_size, void* d_ws, size_t ws_size,
                              hipStream_t stream) {
    (void)in_sizes; (void)n_in; (void)out_size;
    const float* x  = (const float*)d_in[0];
    const float* Wq = (const float*)d_in[1];
    const float* bq = (const float*)d_in[2];
    const float* Wk = (const float*)d_in[3];
    const float* bk = (const float*)d_in[4];
    const float* Wv = (const float*)d_in[5];
    const float* bv = (const float*)d_in[6];
    const float* Wp = (const float*)d_in[7];
    const float* bp = (const float*)d_in[8];

    char* p = (char*)d_ws;
    auto alloc = [&](size_t elems, size_t esz) -> void* {
        void* r = (void*)p;
        p += (elems * esz + 255) & ~(size_t)255;
        return r;
    };
    const size_t nx  = (size_t)NB * NS * ND;   // 6291456
    const size_t nw  = (size_t)NH * ND * ND;   // 7077888

    // ---- ws_size-adaptive configuration (pure function of ws_size) ----
    const size_t fixedA = 2 * (nx * 2 + 256) + 6 * (nw * 2 + 256);
    const size_t o2full = (size_t)NB * NS * NHD * 2 + 256;   // 151.0 MB
    const size_t o2one  = (size_t)NS * NHD * 2 + 256;        //  18.9 MB
    const size_t chunk1 = 5 * ((size_t)NS * ND * 2 + 256)    //  14.2 MB per head
                        + ((size_t)NS * NS * 4 + 256)
                        + ((size_t)NS * NS * 2 + 256);
    const size_t slop = 1u << 20;
    const int cands[4] = {12, 4, 2, 1};
    int HG = 1; bool fullO2 = false;
    for (int i = 0; i < 4; i++)
        if (fixedA + o2full + (size_t)cands[i] * chunk1 + slop <= ws_size) {
            HG = cands[i]; fullO2 = true; break;
        }
    if (!fullO2)
        for (int i = 2; i < 4; i++)
            if (fixedA + o2one + (size_t)cands[i] * chunk1 + slop <= ws_size) {
                HG = cands[i]; break;
            }
    const int NCH = NH / HG;

    unsigned short* xh   = (unsigned short*)alloc(nx, 2);
    unsigned short* xl   = (unsigned short*)alloc(nx, 2);
    unsigned short* WqTh = (unsigned short*)alloc(nw, 2);
    unsigned short* WqTl = (unsigned short*)alloc(nw, 2);
    unsigned short* WkTh = (unsigned short*)alloc(nw, 2);
    unsigned short* WkTl = (unsigned short*)alloc(nw, 2);
    unsigned short* WvT  = (unsigned short*)alloc(nw, 2);
    unsigned short* WpT  = (unsigned short*)alloc(nw, 2);
    unsigned short* O2   = (unsigned short*)alloc(fullO2 ? (size_t)NB * NS * NHD
                                                         : (size_t)NS * NHD, 2);
    unsigned short* Qh   = (unsigned short*)alloc((size_t)HG * NS * ND, 2);
    unsigned short* Ql   = (unsigned short*)alloc((size_t)HG * NS * ND, 2);
    unsigned short* Kh   = (unsigned short*)alloc((size_t)HG * NS * ND, 2);
    unsigned short* Kl   = (unsigned short*)alloc((size_t)HG * NS * ND, 2);
    unsigned short* VT   = (unsigned short*)alloc((size_t)HG * NS * ND, 2);
    float*          Sc   = (float*)alloc((size_t)HG * NS * NS, 4);
    unsigned short* Pm   = (unsigned short*)alloc((size_t)HG * NS * NS, 2);

    k_split<<<(int)(nx / 4 / 256), 256, 0, stream>>>(x, xh, xl, (int)(nx / 4));
    k_transpose<true ><<<dim3(12, 12, 12), 256, 0, stream>>>(Wq, WqTh, WqTl, ND, ND);
    k_transpose<true ><<<dim3(12, 12, 12), 256, 0, stream>>>(Wk, WkTh, WkTl, ND, ND);
    k_transpose<false><<<dim3(12, 12, 12), 256, 0, stream>>>(Wv, WvT, nullptr, ND, ND);
    k_transpose<false><<<dim3(12, 144, 1), 256, 0, stream>>>(Wp, WpT, nullptr, NHD, ND);

    for (int b = 0; b < NB; b++) {
        const unsigned short* xbh = xh + (size_t)b * NS * ND;
        const unsigned short* xbl = xl + (size_t)b * NS * ND;
        unsigned short* O2b = O2 + (fullO2 ? (size_t)b * NS * NHD : 0);
        for (int g = 0; g < NCH; g++) {
            const int h0 = g * HG;
            k_proj_qk<<<dim3(6, 8, HG), 256, 0, stream>>>(xbh, xbl, WqTh, WqTl, bq, Qh, Ql, h0);
            k_proj_qk<<<dim3(6, 8, HG), 256, 0, stream>>>(xbh, xbl, WkTh, WkTl, bk, Kh, Kl, h0);
            k_proj_v <<<dim3(6, 8, HG), 256, 0, stream>>>(xbh, WvT, bv, VT, h0);
            k_scores <<<dim3(8, 8, HG), 256, 0, stream>>>(Qh, Ql, Kh, Kl, Sc);
            k_softmax<<<HG * NS / 4, 256, 0, stream>>>(Sc, Pm);
            k_pv     <<<dim3(6, 8, HG), 256, 0, stream>>>(Pm, VT, O2b, h0);
        }
        if (!fullO2)
            k_out<<<dim3(6, 8), 256, 0, stream>>>(O2b, WpT, bp,
                                                  (float*)d_out + (size_t)b * NS * ND);
    }
    if (fullO2)
        k_out<<<dim3(6, 64), 256, 0, stream>>>(O2, WpT, bp, (float*)d_out);
}

// Round 3
// 2941.706 us; speedup vs baseline: 3.4807x; 3.4807x over previous
//
#include <hip/hip_runtime.h>

// ---------------------------------------------------------------------------
// MultiHeadAttention (full-width per-head projections), MI355X gfx950.
// Round 3: head-major batch-merged restructure (big grids, ~129 MB workspace)
// + m97-style global_load_lds staging in the GEMM core.
// Math unchanged from round 2 (3-term bf16 hi/lo split for Q/K proj and QK^T;
// fp32 softmax in-place; bf16 V/PV; fp32 out-proj accumulated in d_out).
// ---------------------------------------------------------------------------

typedef __attribute__((ext_vector_type(8))) short bf16x8;
typedef __attribute__((ext_vector_type(4))) float fx4;

#define NB 8
#define NS 1024
#define ND 768
#define NH 12

__device__ __forceinline__ unsigned short f2bf(float x) {
    unsigned int u = __float_as_uint(x);
    u += 0x7fffu + ((u >> 16) & 1u);   // round-to-nearest-even bf16
    return (unsigned short)(u >> 16);
}
__device__ __forceinline__ float bf2f(unsigned short h) {
    return __uint_as_float(((unsigned int)h) << 16);
}

// async global->LDS, 16B per lane; LDS base must be wave-uniform.
__device__ __forceinline__ void gll16(const void* g, void* l) {
    __builtin_amdgcn_global_load_lds(
        (const __attribute__((address_space(1))) void*)g,
        (__attribute__((address_space(3))) void*)l, 16, 0, 0);
}

// ---------------- elementwise split: f32 -> bf16 hi + bf16 lo ----------------
__global__ void k_split(const float* __restrict__ in, unsigned short* __restrict__ hi,
                        unsigned short* __restrict__ lo, int n4) {
    int i = blockIdx.x * 256 + threadIdx.x;
    if (i >= n4) return;
    float4 v = ((const float4*)in)[i];
    ushort4 h, l;
    h.x = f2bf(v.x); l.x = f2bf(v.x - bf2f(h.x));
    h.y = f2bf(v.y); l.y = f2bf(v.y - bf2f(h.y));
    h.z = f2bf(v.z); l.z = f2bf(v.z - bf2f(h.z));
    h.w = f2bf(v.w); l.w = f2bf(v.w - bf2f(h.w));
    ((ushort4*)hi)[i] = h;
    ((ushort4*)lo)[i] = l;
}

// ---- per-head fused weight transpose: Wq(split), Wk(split), Wv, Wp_h --------
// each mode transposes a 768x768 f32 block -> bf16 (hi[,lo]) [e][d] k-contig.
__global__ void k_transpose_head(
    const float* __restrict__ Wq, const float* __restrict__ Wk,
    const float* __restrict__ Wv, const float* __restrict__ Wp, int h,
    unsigned short* __restrict__ qTh, unsigned short* __restrict__ qTl,
    unsigned short* __restrict__ kTh, unsigned short* __restrict__ kTl,
    unsigned short* __restrict__ vT, unsigned short* __restrict__ pT)
{
    const long hw = (long)h * ND * ND;
    const float* in; unsigned short *oh, *ol; bool split;
    switch (blockIdx.z) {
        case 0:  in = Wq + hw; oh = qTh; ol = qTl; split = true;  break;
        case 1:  in = Wk + hw; oh = kTh; ol = kTl; split = true;  break;
        case 2:  in = Wv + hw; oh = vT;  ol = nullptr; split = false; break;
        default: in = Wp + hw; oh = pT;  ol = nullptr; split = false; break;
    }
    __shared__ float tile[64][65];
    int c0 = blockIdx.x * 64, r0 = blockIdx.y * 64;
    int tc = threadIdx.x & 63, t4 = threadIdx.x >> 6;
    #pragma unroll
    for (int i = 0; i < 16; i++) {
        int r = (i << 2) + t4;
        tile[r][tc] = in[(long)(r0 + r) * ND + c0 + tc];
    }
    __syncthreads();
    #pragma unroll
    for (int i = 0; i < 16; i++) {
        int c = (i << 2) + t4;
        float v = tile[tc][c];
        long o = (long)(c0 + c) * ND + r0 + tc;
        unsigned short hh = f2bf(v);
        oh[o] = hh;
        if (split) ol[o] = f2bf(v - bf2f(hh));
    }
}

// ---------------------------------------------------------------------------
// MFMA GEMM core, m97 structure: 128x128 tile, BK=32, 4 waves (2x2),
// linear LDS [128 rows][32 bf16], global_load_lds width-16 staging,
// 2-barrier K-loop, acc 4x4 frags of 16x16x32.
// A row-major [*, lda] k-contig; B as BT row-major [n, ldb] k-contig.
// NTERMS==3: Ah*Bh + Ah*Bl + Al*Bh (split-bf16 product).
// C/D layout (HW-verified): col = lane&15, row = (lane>>4)*4 + reg.
// ---------------------------------------------------------------------------
template<int NTERMS, class Epi>
__device__ __forceinline__ void gemm_core(
    const unsigned short* __restrict__ Ah, const unsigned short* __restrict__ Al, int lda,
    const unsigned short* __restrict__ Bh, const unsigned short* __restrict__ Bl, int ldb,
    int K, Epi epi)
{
    constexpr int NT = (NTERMS == 3) ? 4 : 2;
    __shared__ __align__(16) unsigned short sm[NT][4096];   // 8KB per tile

    const int t = threadIdx.x;
    const int lane = t & 63;
    const int w = t >> 6;
    const int wm = (w >> 1) << 6;
    const int wn = (w & 1) << 6;
    const int lr = lane & 15;
    const int lg = lane >> 4;

    // staging: wave w stages LDS rows [w*32, w*32+32) of each tile in two
    // 1KB instructions; lane covers row w*32 + c*16 + (lane>>2), 16B chunk (lane&3)
    const int srA = (w << 5) + (lane >> 2);
    const int skb = (lane & 3) << 4;
    const int ldso = w << 11;                   // LDS byte offset (wave-uniform)

    const long ga0 = (long)srA * lda * 2 + skb;
    const long ga1 = ga0 + (long)(lda << 5);    // +16 rows
    const long gb0 = (long)srA * ldb * 2 + skb;
    const long gb1 = gb0 + (long)(ldb << 5);

    const char* pAh = (const char*)Ah;
    const char* pBh = (const char*)Bh;
    const char* pAl = (const char*)Al;
    const char* pBl = (const char*)Bl;
    char* smA = (char*)&sm[0][0];
    char* smB = (char*)&sm[1][0];
    char* smA2 = (char*)&sm[NT - 2][0];
    char* smB2 = (char*)&sm[NT - 1][0];

    int offA[4], offB[4];
    #pragma unroll
    for (int i = 0; i < 4; i++) {
        offA[i] = (wm + (i << 4) + lr) * 32 + (lg << 3);   // ushort index
        offB[i] = (wn + (i << 4) + lr) * 32 + (lg << 3);
    }

    fx4 acc[4][4] = {};

    for (int k0 = 0; k0 < K; k0 += 32) {
        const long kb2 = (long)k0 * 2;
        __syncthreads();
        gll16(pAh + ga0 + kb2, smA + ldso);
        gll16(pAh + ga1 + kb2, smA + ldso + 1024);
        gll16(pBh + gb0 + kb2, smB + ldso);
        gll16(pBh + gb1 + kb2, smB + ldso + 1024);
        if constexpr (NTERMS == 3) {
            gll16(pAl + ga0 + kb2, smA2 + ldso);
            gll16(pAl + ga1 + kb2, smA2 + ldso + 1024);
            gll16(pBl + gb0 + kb2, smB2 + ldso);
            gll16(pBl + gb1 + kb2, smB2 + ldso + 1024);
        }
        __syncthreads();

        bf16x8 fa[4], fb[4], fa2[4], fb2[4];
        #pragma unroll
        for (int i = 0; i < 4; i++) {
            fa[i] = *(const bf16x8*)&sm[0][offA[i]];
            fb[i] = *(const bf16x8*)&sm[1][offB[i]];
        }
        if constexpr (NTERMS == 3) {
            #pragma unroll
            for (int i = 0; i < 4; i++) {
                fa2[i] = *(const bf16x8*)&sm[2][offA[i]];
                fb2[i] = *(const bf16x8*)&sm[3][offB[i]];
            }
        }
        #pragma unroll
        for (int i = 0; i < 4; i++)
            #pragma unroll
            for (int j = 0; j < 4; j++) {
                acc[i][j] = __builtin_amdgcn_mfma_f32_16x16x32_bf16(fa[i], fb[j], acc[i][j], 0, 0, 0);
                if constexpr (NTERMS == 3) {
                    acc[i][j] = __builtin_amdgcn_mfma_f32_16x16x32_bf16(fa[i], fb2[j], acc[i][j], 0, 0, 0);
                    acc[i][j] = __builtin_amdgcn_mfma_f32_16x16x32_bf16(fa2[i], fb[j], acc[i][j], 0, 0, 0);
                }
            }
    }

    #pragma unroll
    for (int i = 0; i < 4; i++)
        #pragma unroll
        for (int j = 0; j < 4; j++)
            #pragma unroll
            for (int r = 0; r < 4; r++)
                epi(wm + (i << 4) + (lg << 2) + r, wn + (j << 4) + lr, acc[i][j][r]);
}

// ------------------------- GEMM wrapper kernels ------------------------------

// Q/K projection (split output). A rows = BC*1024 of x-chunk. grid (6, BC*8)
__global__ __launch_bounds__(256, 2) void k_proj_qk(
    const unsigned short* __restrict__ xh, const unsigned short* __restrict__ xl,
    const unsigned short* __restrict__ WTh, const unsigned short* __restrict__ WTl,
    const float* __restrict__ bias,
    unsigned short* __restrict__ Oh, unsigned short* __restrict__ Ol)
{
    const int m0 = blockIdx.y << 7;
    const int n0 = blockIdx.x << 7;
    const unsigned short* A  = xh + (long)m0 * ND;
    const unsigned short* A2 = xl + (long)m0 * ND;
    const unsigned short* B  = WTh + (long)n0 * ND;
    const unsigned short* B2 = WTl + (long)n0 * ND;
    unsigned short* oh = Oh + (long)m0 * ND + n0;
    unsigned short* ol = Ol + (long)m0 * ND + n0;
    const float* bi = bias + n0;
    gemm_core<3>(A, A2, ND, B, B2, ND, ND, [=](int r, int c, float v) {
        v += bi[c];
        unsigned short hh = f2bf(v);
        oh[(long)r * ND + c] = hh;
        ol[(long)r * ND + c] = f2bf(v - bf2f(hh));
    });
}

// V projection -> V^T[bl][e][t] bf16. grid (6, BC*8)
__global__ __launch_bounds__(256, 2) void k_proj_v(
    const unsigned short* __restrict__ xh, const unsigned short* __restrict__ WTh,
    const float* __restrict__ bias, unsigned short* __restrict__ VT)
{
    const int m0 = blockIdx.y << 7;
    const int n0 = blockIdx.x << 7;
    const int bl = m0 >> 10;                 // batch within chunk
    const int s0 = m0 & (NS - 1);
    const unsigned short* A = xh + (long)m0 * ND;
    const unsigned short* B = WTh + (long)n0 * ND;
    unsigned short* vt = VT + (long)bl * ND * NS;
    const float* bi = bias + n0;
    gemm_core<1>(A, nullptr, ND, B, nullptr, ND, ND, [=](int r, int c, float v) {
        vt[(long)(n0 + c) * NS + s0 + r] = f2bf(v + bi[c]);
    });
}

// scores (fp32, unscaled) per batch of chunk. grid (8, 8, BC)
__global__ __launch_bounds__(256, 2) void k_scores(
    const unsigned short* __restrict__ Qh, const unsigned short* __restrict__ Ql,
    const unsigned short* __restrict__ Kh, const unsigned short* __restrict__ Kl,
    float* __restrict__ Sc)
{
    const int bl = blockIdx.z;
    const int m0 = blockIdx.y << 7;
    const int n0 = blockIdx.x << 7;
    const long qo = ((long)bl * NS + m0) * ND;
    const long ko = ((long)bl * NS + n0) * ND;
    float* out = Sc + ((long)bl * NS + m0) * NS + n0;
    gemm_core<3>(Qh + qo, Ql + qo, ND, Kh + ko, Kl + ko, ND, ND,
                 [=](int r, int c, float v) { out[(long)r * NS + c] = v; });
}

// row softmax of 8*score, fp32 -> bf16 IN PLACE (P row at start of Sc row).
// one wave per row; grid (BC*256), block 256.
__global__ __launch_bounds__(256) void k_softmax(float* __restrict__ Sc) {
    int row = blockIdx.x * 4 + (threadIdx.x >> 6);
    int lane = threadIdx.x & 63;
    float* rp = Sc + (long)row * NS;
    const float4* src = (const float4*)rp + (lane << 2);
    float v[16];
    #pragma unroll
    for (int i = 0; i < 4; i++) {
        float4 a = src[i];
        v[i * 4 + 0] = a.x; v[i * 4 + 1] = a.y; v[i * 4 + 2] = a.z; v[i * 4 + 3] = a.w;
    }
    float m = v[0];
    #pragma unroll
    for (int i = 1; i < 16; i++) m = fmaxf(m, v[i]);
    #pragma unroll
    for (int o = 32; o > 0; o >>= 1) m = fmaxf(m, __shfl_xor(m, o));
    float s = 0.f, p[16];
    #pragma unroll
    for (int i = 0; i < 16; i++) { p[i] = __expf((v[i] - m) * 8.0f); s += p[i]; }
    #pragma unroll
    for (int o = 32; o > 0; o >>= 1) s += __shfl_xor(s, o);
    float inv = 1.0f / s;
    unsigned int wrd[8];
    #pragma unroll
    for (int i = 0; i < 8; i++) {
        unsigned int u0 = f2bf(p[2 * i] * inv);
        unsigned int u1 = f2bf(p[2 * i + 1] * inv);
        wrd[i] = u0 | (u1 << 16);
    }
    // shuffle reductions above guarantee all lanes' loads completed before stores
    uint4* dst = (uint4*)((unsigned short*)rp + (lane << 4));
    dst[0] = make_uint4(wrd[0], wrd[1], wrd[2], wrd[3]);
    dst[1] = make_uint4(wrd[4], wrd[5], wrd[6], wrd[7]);
}

// O = P @ V (bf16 out, O overlays dead Q buffer). grid (6, 8, BC)
// P rows have stride 2048 ushorts (bf16 packed at head of fp32 Sc rows).
__global__ __launch_bounds__(256, 2) void k_pv(
    const unsigned short* __restrict__ P, const unsigned short* __restrict__ VT,
    unsigned short* __restrict__ O)
{
    const int bl = blockIdx.z;
    const int m0 = blockIdx.y << 7;
    const int n0 = blockIdx.x << 7;
    const unsigned short* A = P + ((long)bl * NS + m0) * (2 * NS);
    const unsigned short* B = VT + (long)bl * ND * NS + (long)n0 * NS;
    unsigned short* out = O + ((long)bl * NS + m0) * ND + n0;
    gemm_core<1>(A, nullptr, 2 * NS, B, nullptr, NS, NS, [=](int r, int c, float v) {
        out[(long)r * ND + c] = f2bf(v);
    });
}

// out-proj accumulate into d_out (fp32): MODE 0 = write, 1 = +=, 2 = += +bias.
// grid (6, BC*8)
template<int MODE>
__global__ __launch_bounds__(256, 2) void k_out(
    const unsigned short* __restrict__ O, const unsigned short* __restrict__ WpT,
    const float* __restrict__ bp, float* __restrict__ outp)
{
    const int m0 = blockIdx.y << 7;
    const int n0 = blockIdx.x << 7;
    const unsigned short* A = O + (long)m0 * ND;
    const unsigned short* B = WpT + (long)n0 * ND;
    float* o = outp + (long)m0 * ND + n0;
    const float* bi = bp + n0;
    gemm_core<1>(A, nullptr, ND, B, nullptr, ND, ND, [=](int r, int c, float v) {
        float* d = o + (long)r * ND + c;
        if constexpr (MODE == 0) *d = v;
        else if constexpr (MODE == 1) *d += v;
        else *d = *d + v + bi[c];
    });
}

// ---------------------------------------------------------------------------

extern "C" void kernel_launch(void* const* d_in, const int* in_sizes, int n_in,
                              void* d_out, int out_size, void* d_ws, size_t ws_size,
                              hipStream_t stream) {
    (void)in_sizes; (void)n_in; (void)out_size;
    const float* x  = (const float*)d_in[0];
    const float* Wq = (const float*)d_in[1];
    const float* bq = (const float*)d_in[2];
    const float* Wk = (const float*)d_in[3];
    const float* bk = (const float*)d_in[4];
    const float* Wv = (const float*)d_in[5];
    const float* bv = (const float*)d_in[6];
    const float* Wp = (const float*)d_in[7];
    const float* bp = (const float*)d_in[8];

    char* p = (char*)d_ws;
    auto alloc = [&](size_t bytes) -> void* {
        void* r = (void*)p;
        p += (bytes + 255) & ~(size_t)255;
        return r;
    };
    const size_t nx = (size_t)NB * NS * ND;           // x elems
    const size_t nwh = (size_t)ND * ND;               // per-head weight elems
    const size_t perb_qkv = (size_t)NS * ND * 2;      // bytes, one batch one buffer
    const size_t perb_sc  = (size_t)NS * NS * 4;

    // ---- batch-chunk ladder (pure function of ws_size) ----
    const size_t fixedB = 2 * (nx * 2 + 256) + 6 * (nwh * 2 + 256);
    const size_t chunkB = 5 * (perb_qkv + 256) + (perb_sc + 256);
    int BC = 1;
    for (int c = 8; c >= 1; c >>= 1)
        if (fixedB + (size_t)c * chunkB + (1u << 20) <= ws_size) { BC = c; break; }
    const int NCH = NB / BC;

    unsigned short* xh   = (unsigned short*)alloc(nx * 2);
    unsigned short* xl   = (unsigned short*)alloc(nx * 2);
    unsigned short* wqTh = (unsigned short*)alloc(nwh * 2);
    unsigned short* wqTl = (unsigned short*)alloc(nwh * 2);
    unsigned short* wkTh = (unsigned short*)alloc(nwh * 2);
    unsigned short* wkTl = (unsigned short*)alloc(nwh * 2);
    unsigned short* wvT  = (unsigned short*)alloc(nwh * 2);
    unsigned short* wpT  = (unsigned short*)alloc(nwh * 2);
    unsigned short* Qh   = (unsigned short*)alloc((size_t)BC * perb_qkv);
    unsigned short* Ql   = (unsigned short*)alloc((size_t)BC * perb_qkv);
    unsigned short* Kh   = (unsigned short*)alloc((size_t)BC * perb_qkv);
    unsigned short* Kl   = (unsigned short*)alloc((size_t)BC * perb_qkv);
    unsigned short* VT   = (unsigned short*)alloc((size_t)BC * perb_qkv);
    float*          Sc   = (float*)alloc((size_t)BC * perb_sc);
    unsigned short* O    = Qh;   // overlays dead Q after scores

    k_split<<<(int)(nx / 4 / 256), 256, 0, stream>>>(x, xh, xl, (int)(nx / 4));

    for (int h = 0; h < NH; h++) {
        k_transpose_head<<<dim3(12, 12, 4), 256, 0, stream>>>(
            Wq, Wk, Wv, Wp, h, wqTh, wqTl, wkTh, wkTl, wvT, wpT);
        for (int ch = 0; ch < NCH; ch++) {
            const long rowoff = (long)ch * BC * NS;
            const unsigned short* xch = xh + rowoff * ND;
            const unsigned short* xcl = xl + rowoff * ND;
            k_proj_qk<<<dim3(6, BC * 8), 256, 0, stream>>>(xch, xcl, wqTh, wqTl,
                                                           bq + h * ND, Qh, Ql);
            k_proj_qk<<<dim3(6, BC * 8), 256, 0, stream>>>(xch, xcl, wkTh, wkTl,
                                                           bk + h * ND, Kh, Kl);
            k_proj_v <<<dim3(6, BC * 8), 256, 0, stream>>>(xch, wvT, bv + h * ND, VT);
            k_scores <<<dim3(8, 8, BC), 256, 0, stream>>>(Qh, Ql, Kh, Kl, Sc);
            k_softmax<<<BC * 256, 256, 0, stream>>>(Sc);
            k_pv     <<<dim3(6, 8, BC), 256, 0, stream>>>((unsigned short*)Sc, VT, O);
            float* oc = (float*)d_out + rowoff * ND;
            if (h == 0)
                k_out<0><<<dim3(6, BC * 8), 256, 0, stream>>>(O, wpT, bp, oc);
            else if (h == NH - 1)
                k_out<2><<<dim3(6, BC * 8), 256, 0, stream>>>(O, wpT, bp, oc);
            else
                k_out<1><<<dim3(6, BC * 8), 256, 0, stream>>>(O, wpT, bp, oc);
        }
    }
}

// Round 4
// 2002.188 us; speedup vs baseline: 5.1140x; 1.4692x over previous
//
#include <hip/hip_runtime.h>

// ---------------------------------------------------------------------------
// MultiHeadAttention (full-width per-head projections), MI355X gfx950.
// Round 4: algebraic refactor + restored LDS swizzle.
//   scores = softmax_t( 8*( x M_h x^T + w_t ) ),  M_h = Wq_h Wk_h^T
//   (query-side bias terms cancel in softmax; w = x*(Wk_h bq_h) survives)
//   out    = sum_h P_h Z_h + bp,  Z_h = x N_h + bv_h Wp_h,  N_h = Wv_h Wp_h
// Executed FLOPs 1.13e12 (was 1.55e12). gemm_core: 128x128/BK=32/4-wave with
// global_load_lds (linear LDS dest) + inverse-swizzled global source +
// swizzled ds_read (chunk ^= (row>>1)&3) -> conflict-floor.
// Workspace 139.4 MB (< proven ws_size >= 143.1 MB from round 2).
// ---------------------------------------------------------------------------

typedef __attribute__((ext_vector_type(8))) short bf16x8;
typedef __attribute__((ext_vector_type(4))) float fx4;

#define NB 8
#define NS 1024
#define ND 768
#define NH 12

__device__ __forceinline__ unsigned short f2bf(float x) {
    unsigned int u = __float_as_uint(x);
    u += 0x7fffu + ((u >> 16) & 1u);   // round-to-nearest-even bf16
    return (unsigned short)(u >> 16);
}
__device__ __forceinline__ float bf2f(unsigned short h) {
    return __uint_as_float(((unsigned int)h) << 16);
}

// async global->LDS, 16B per lane; LDS base must be wave-uniform.
__device__ __forceinline__ void gll16(const void* g, void* l) {
    __builtin_amdgcn_global_load_lds(
        (const __attribute__((address_space(1))) void*)g,
        (__attribute__((address_space(3))) void*)l, 16, 0, 0);
}

// ---------------- elementwise: f32 -> bf16 hi + bf16 lo ----------------------
__global__ void k_split(const float* __restrict__ in, unsigned short* __restrict__ hi,
                        unsigned short* __restrict__ lo, int n4) {
    int i = blockIdx.x * 256 + threadIdx.x;
    if (i >= n4) return;
    float4 v = ((const float4*)in)[i];
    ushort4 h, l;
    h.x = f2bf(v.x); l.x = f2bf(v.x - bf2f(h.x));
    h.y = f2bf(v.y); l.y = f2bf(v.y - bf2f(h.y));
    h.z = f2bf(v.z); l.z = f2bf(v.z - bf2f(h.z));
    h.w = f2bf(v.w); l.w = f2bf(v.w - bf2f(h.w));
    ((ushort4*)hi)[i] = h;
    ((ushort4*)lo)[i] = l;
}

// ---------------- elementwise: f32 -> bf16 -----------------------------------
__global__ void k_castbf(const float* __restrict__ in, unsigned short* __restrict__ out,
                         int n4) {
    int i = blockIdx.x * 256 + threadIdx.x;
    if (i >= n4) return;
    float4 v = ((const float4*)in)[i];
    ushort4 h;
    h.x = f2bf(v.x); h.y = f2bf(v.y); h.z = f2bf(v.z); h.w = f2bf(v.w);
    ((ushort4*)out)[i] = h;
}

// ---------------- transpose f32 [z][R][C] -> bf16 [z][C][R] ------------------
__global__ void k_transpose(const float* __restrict__ in, unsigned short* __restrict__ oh,
                            int R, int C) {
    __shared__ float tile[64][65];
    long zo = (long)blockIdx.z * R * C;
    in += zo; oh += zo;
    int c0 = blockIdx.x * 64, r0 = blockIdx.y * 64;
    int tc = threadIdx.x & 63, t4 = threadIdx.x >> 6;
    #pragma unroll
    for (int i = 0; i < 16; i++) {
        int r = (i << 2) + t4;
        tile[r][tc] = in[(long)(r0 + r) * C + c0 + tc];
    }
    __syncthreads();
    #pragma unroll
    for (int i = 0; i < 16; i++) {
        int c = (i << 2) + t4;
        oh[(long)(c0 + c) * R + r0 + tc] = f2bf(tile[tc][c]);
    }
}

// ---- rk[h][d] = sum_e Wk[h,d,e]*bq[h,e]  (wave per (h,d)) -------------------
__global__ __launch_bounds__(256) void k_rk(const float* __restrict__ Wk,
                                            const float* __restrict__ bq,
                                            float* __restrict__ rk) {
    int h = blockIdx.y;
    int d = blockIdx.x * 4 + (threadIdx.x >> 6);
    int lane = threadIdx.x & 63;
    const float4* row = (const float4*)(Wk + ((long)h * ND + d) * ND);
    const float4* bv4 = (const float4*)(bq + h * ND);
    float acc = 0.f;
    #pragma unroll
    for (int i = 0; i < 3; i++) {
        float4 a = row[lane + (i << 6)];
        float4 b = bv4[lane + (i << 6)];
        acc += a.x * b.x + a.y * b.y + a.z * b.z + a.w * b.w;
    }
    #pragma unroll
    for (int o = 32; o > 0; o >>= 1) acc += __shfl_xor(acc, o);
    if (lane == 0) rk[h * ND + d] = acc;
}

// ---- s_all[h][j] = sum_e bv[h,e]*Wp[h*768+e, j] via WpT (wave per (h,j)) ----
__global__ __launch_bounds__(256) void k_sh(const unsigned short* __restrict__ WpT,
                                            const float* __restrict__ bv,
                                            float* __restrict__ s_all) {
    int h = blockIdx.y;
    int j = blockIdx.x * 4 + (threadIdx.x >> 6);
    int lane = threadIdx.x & 63;
    const ushort4* row = (const ushort4*)(WpT + ((long)h * ND + j) * ND);
    const float* bvh = bv + h * ND;
    float acc = 0.f;
    #pragma unroll
    for (int i = 0; i < 3; i++) {
        int c = lane + (i << 6);
        ushort4 u = row[c];
        int e = c << 2;
        acc += bf2f(u.x) * bvh[e] + bf2f(u.y) * bvh[e + 1]
             + bf2f(u.z) * bvh[e + 2] + bf2f(u.w) * bvh[e + 3];
    }
    #pragma unroll
    for (int o = 32; o > 0; o >>= 1) acc += __shfl_xor(acc, o);
    if (lane == 0) s_all[h * ND + j] = acc;
}

// ---- w_all[h][s] = x_s . rk[h]  (wave per row, rk staged in LDS) ------------
__global__ __launch_bounds__(256) void k_w(const float* __restrict__ x,
                                           const float* __restrict__ rk,
                                           float* __restrict__ w_all) {
    __shared__ float srk[NH * ND];
    for (int i = threadIdx.x; i < NH * ND; i += 256) srk[i] = rk[i];
    __syncthreads();
    int row = blockIdx.x * 4 + (threadIdx.x >> 6);
    int lane = threadIdx.x & 63;
    const float4* xr = (const float4*)(x + (long)row * ND);
    float4 xa[3];
    #pragma unroll
    for (int i = 0; i < 3; i++) xa[i] = xr[lane + (i << 6)];
    for (int h = 0; h < NH; h++) {
        const float* r = srk + h * ND;
        float acc = 0.f;
        #pragma unroll
        for (int i = 0; i < 3; i++) {
            int e = (lane + (i << 6)) << 2;
            acc += xa[i].x * r[e] + xa[i].y * r[e + 1]
                 + xa[i].z * r[e + 2] + xa[i].w * r[e + 3];
        }
        #pragma unroll
        for (int o = 32; o > 0; o >>= 1) acc += __shfl_xor(acc, o);
        if (lane == 0) w_all[h * (NB * NS) + row] = acc;
    }
}

// ---------------------------------------------------------------------------
// MFMA GEMM core: 128x128 tile, BK=32, 4 waves (2x2), global_load_lds staging
// with inverse-swizzled SOURCE (chunk ^= (row>>1)&3), linear LDS dest,
// swizzled ds_read -> 2-way (free) bank aliasing.
// A row-major [*, lda] k-contig; B as BT row-major [n, ldb] k-contig.
// NTERMS==3: Ah*Bh + Ah*Bl + Al*Bh (split-bf16 product).
// C/D layout (HW-verified): col = lane&15, row = (lane>>4)*4 + reg.
// ---------------------------------------------------------------------------
template<int NTERMS, class Epi>
__device__ __forceinline__ void gemm_core(
    const unsigned short* __restrict__ Ah, const unsigned short* __restrict__ Al, int lda,
    const unsigned short* __restrict__ Bh, const unsigned short* __restrict__ Bl, int ldb,
    int K, Epi epi)
{
    constexpr int NT = (NTERMS == 3) ? 4 : 2;
    __shared__ __align__(16) unsigned short sm[NT][4096];

    const int t = threadIdx.x;
    const int lane = t & 63;
    const int w = t >> 6;
    const int wm = (w >> 1) << 6;
    const int wn = (w & 1) << 6;
    const int lr = lane & 15;
    const int lg = lane >> 4;

    // staging: lane covers row w*32 + (lane>>2) (+16 for 2nd instr),
    // global 16B chunk index = (lane&3) ^ ((row>>1)&3); LDS dest linear.
    const int srA = (w << 5) + (lane >> 2);
    const int swz = (srA >> 1) & 3;
    const int skb = (((lane & 3) ^ swz) << 4);
    const int ldso = w << 11;                   // wave-uniform LDS byte offset

    const long ga0 = (long)srA * lda * 2 + skb;
    const long ga1 = ga0 + (long)lda * 32;      // +16 rows (bytes)
    const long gb0 = (long)srA * ldb * 2 + skb;
    const long gb1 = gb0 + (long)ldb * 32;

    const char* pAh = (const char*)Ah;
    const char* pBh = (const char*)Bh;
    const char* pAl = (const char*)Al;
    const char* pBl = (const char*)Bl;
    char* smA = (char*)&sm[0][0];
    char* smB = (char*)&sm[1][0];
    char* smA2 = (char*)&sm[NT - 2][0];
    char* smB2 = (char*)&sm[NT - 1][0];

    int offA[4], offB[4];
    #pragma unroll
    for (int i = 0; i < 4; i++) {
        int ra = wm + (i << 4) + lr;
        offA[i] = ra * 32 + ((lg ^ ((ra >> 1) & 3)) << 3);   // ushort index
        int rb = wn + (i << 4) + lr;
        offB[i] = rb * 32 + ((lg ^ ((rb >> 1) & 3)) << 3);
    }

    fx4 acc[4][4] = {};

    for (int k0 = 0; k0 < K; k0 += 32) {
        const long kb2 = (long)k0 * 2;
        __syncthreads();
        gll16(pAh + ga0 + kb2, smA + ldso);
        gll16(pAh + ga1 + kb2, smA + ldso + 1024);
        gll16(pBh + gb0 + kb2, smB + ldso);
        gll16(pBh + gb1 + kb2, smB + ldso + 1024);
        if constexpr (NTERMS == 3) {
            gll16(pAl + ga0 + kb2, smA2 + ldso);
            gll16(pAl + ga1 + kb2, smA2 + ldso + 1024);
            gll16(pBl + gb0 + kb2, smB2 + ldso);
            gll16(pBl + gb1 + kb2, smB2 + ldso + 1024);
        }
        __syncthreads();

        bf16x8 fa[4], fb[4], fa2[4], fb2[4];
        #pragma unroll
        for (int i = 0; i < 4; i++) {
            fa[i] = *(const bf16x8*)&sm[0][offA[i]];
            fb[i] = *(const bf16x8*)&sm[1][offB[i]];
        }
        if constexpr (NTERMS == 3) {
            #pragma unroll
            for (int i = 0; i < 4; i++) {
                fa2[i] = *(const bf16x8*)&sm[2][offA[i]];
                fb2[i] = *(const bf16x8*)&sm[3][offB[i]];
            }
        }
        #pragma unroll
        for (int i = 0; i < 4; i++)
            #pragma unroll
            for (int j = 0; j < 4; j++) {
                acc[i][j] = __builtin_amdgcn_mfma_f32_16x16x32_bf16(fa[i], fb[j], acc[i][j], 0, 0, 0);
                if constexpr (NTERMS == 3) {
                    acc[i][j] = __builtin_amdgcn_mfma_f32_16x16x32_bf16(fa[i], fb2[j], acc[i][j], 0, 0, 0);
                    acc[i][j] = __builtin_amdgcn_mfma_f32_16x16x32_bf16(fa2[i], fb[j], acc[i][j], 0, 0, 0);
                }
            }
    }

    #pragma unroll
    for (int i = 0; i < 4; i++)
        #pragma unroll
        for (int j = 0; j < 4; j++)
            #pragma unroll
            for (int r = 0; r < 4; r++)
                epi(wm + (i << 4) + (lg << 2) + r, wn + (j << 4) + lr, acc[i][j][r]);
}

// ------------------------- GEMM wrapper kernels ------------------------------

// MT_h[r,c] = sum_e Wk_h[r,e]*Wq_h[c,e], split out. grid (6,6,12) 3-term.
__global__ __launch_bounds__(256, 2) void k_MT(
    const unsigned short* __restrict__ Wkh, const unsigned short* __restrict__ Wkl,
    const unsigned short* __restrict__ Wqh, const unsigned short* __restrict__ Wql,
    unsigned short* __restrict__ MTh, unsigned short* __restrict__ MTl)
{
    const long hw = (long)blockIdx.z * (ND * ND);
    const int m0 = blockIdx.y << 7, n0 = blockIdx.x << 7;
    unsigned short* oh = MTh + hw + (long)m0 * ND + n0;
    unsigned short* ol = MTl + hw + (long)m0 * ND + n0;
    gemm_core<3>(Wkh + hw + (long)m0 * ND, Wkl + hw + (long)m0 * ND, ND,
                 Wqh + hw + (long)n0 * ND, Wql + hw + (long)n0 * ND, ND, ND,
                 [=](int r, int c, float v) {
                     unsigned short hh = f2bf(v);
                     oh[r * ND + c] = hh;
                     ol[r * ND + c] = f2bf(v - bf2f(hh));
                 });
}

// NT_h[r=j,c=d] = sum_e WpT_h[j,e]*Wv_h[d,e], bf16 out. grid (6,6,12) 1-term.
__global__ __launch_bounds__(256, 2) void k_NT(
    const unsigned short* __restrict__ WpT, const unsigned short* __restrict__ Wvb,
    unsigned short* __restrict__ NT)
{
    const long hw = (long)blockIdx.z * (ND * ND);
    const int m0 = blockIdx.y << 7, n0 = blockIdx.x << 7;
    unsigned short* o = NT + hw + (long)m0 * ND + n0;
    gemm_core<1>(WpT + hw + (long)m0 * ND, nullptr, ND,
                 Wvb + hw + (long)n0 * ND, nullptr, ND, ND,
                 [=](int r, int c, float v) { o[r * ND + c] = f2bf(v); });
}

// G = x * M_h (split out). grid (6,64). MT pointers pre-offset by head.
__global__ __launch_bounds__(256, 2) void k_G(
    const unsigned short* __restrict__ xh, const unsigned short* __restrict__ xl,
    const unsigned short* __restrict__ MTh, const unsigned short* __restrict__ MTl,
    unsigned short* __restrict__ Gh, unsigned short* __restrict__ Gl)
{
    const int m0 = blockIdx.y << 7, n0 = blockIdx.x << 7;
    unsigned short* oh = Gh + (long)m0 * ND + n0;
    unsigned short* ol = Gl + (long)m0 * ND + n0;
    gemm_core<3>(xh + (long)m0 * ND, xl + (long)m0 * ND, ND,
                 MTh + (long)n0 * ND, MTl + (long)n0 * ND, ND, ND,
                 [=](int r, int c, float v) {
                     unsigned short hh = f2bf(v);
                     oh[(long)r * ND + c] = hh;
                     ol[(long)r * ND + c] = f2bf(v - bf2f(hh));
                 });
}

// scores[bl][s][t] = G_s . x_t + w[t]  (fp32, unscaled). grid (8,8,8).
// wv pre-offset by head (h*8192).
__global__ __launch_bounds__(256, 2) void k_scores(
    const unsigned short* __restrict__ Gh, const unsigned short* __restrict__ Gl,
    const unsigned short* __restrict__ xh, const unsigned short* __restrict__ xl,
    const float* __restrict__ wv, float* __restrict__ Sc)
{
    const int bl = blockIdx.z;
    const int m0 = blockIdx.y << 7, n0 = blockIdx.x << 7;
    const long ao = ((long)bl * NS + m0) * ND;
    const long bo = ((long)bl * NS + n0) * ND;
    const float* ww = wv + bl * NS + n0;
    float* out = Sc + ((long)bl * NS + m0) * NS + n0;
    gemm_core<3>(Gh + ao, Gl + ao, ND, xh + bo, xl + bo, ND, ND,
                 [=](int r, int c, float v) { out[(long)r * NS + c] = v + ww[c]; });
}

// row softmax of 8*score, fp32 -> bf16 IN PLACE. wave per row; grid 2048.
__global__ __launch_bounds__(256) void k_softmax(float* __restrict__ Sc) {
    int row = blockIdx.x * 4 + (threadIdx.x >> 6);
    int lane = threadIdx.x & 63;
    float* rp = Sc + (long)row * NS;
    const float4* src = (const float4*)rp + (lane << 2);
    float v[16];
    #pragma unroll
    for (int i = 0; i < 4; i++) {
        float4 a = src[i];
        v[i * 4 + 0] = a.x; v[i * 4 + 1] = a.y; v[i * 4 + 2] = a.z; v[i * 4 + 3] = a.w;
    }
    float m = v[0];
    #pragma unroll
    for (int i = 1; i < 16; i++) m = fmaxf(m, v[i]);
    #pragma unroll
    for (int o = 32; o > 0; o >>= 1) m = fmaxf(m, __shfl_xor(m, o));
    float s = 0.f, p[16];
    #pragma unroll
    for (int i = 0; i < 16; i++) { p[i] = __expf((v[i] - m) * 8.0f); s += p[i]; }
    #pragma unroll
    for (int o = 32; o > 0; o >>= 1) s += __shfl_xor(s, o);
    float inv = 1.0f / s;
    unsigned int wrd[8];
    #pragma unroll
    for (int i = 0; i < 8; i++) {
        unsigned int u0 = f2bf(p[2 * i] * inv);
        unsigned int u1 = f2bf(p[2 * i + 1] * inv);
        wrd[i] = u0 | (u1 << 16);
    }
    uint4* dst = (uint4*)((unsigned short*)rp + (lane << 4));
    dst[0] = make_uint4(wrd[0], wrd[1], wrd[2], wrd[3]);
    dst[1] = make_uint4(wrd[4], wrd[5], wrd[6], wrd[7]);
}

// Z = x*NT_h + s_h -> ZT[bl][j][t] bf16 (scatter). grid (6,64).
// NT, sh pre-offset by head.
__global__ __launch_bounds__(256, 2) void k_Z(
    const unsigned short* __restrict__ xh, const unsigned short* __restrict__ NT,
    const float* __restrict__ sh, unsigned short* __restrict__ ZT)
{
    const int m0 = blockIdx.y << 7, n0 = blockIdx.x << 7;
    const int bl = m0 >> 10;
    const int s0 = m0 & (NS - 1);
    unsigned short* zt = ZT + (long)bl * (ND * NS);
    gemm_core<1>(xh + (long)m0 * ND, nullptr, ND,
                 NT + (long)n0 * ND, nullptr, ND, ND,
                 [=](int r, int c, float v) {
                     zt[(long)(n0 + c) * NS + s0 + r] = f2bf(v + sh[n0 + c]);
                 });
}

// out += P * Z (fp32 accumulate in d_out). grid (6,8,8).
// P = bf16 packed in Sc rows (stride 2048 ushorts).
template<int MODE>   // 0: first head (write, +bp), 1: accumulate
__global__ __launch_bounds__(256, 2) void k_PV(
    const unsigned short* __restrict__ P, const unsigned short* __restrict__ ZT,
    const float* __restrict__ bp, float* __restrict__ outp)
{
    const int bl = blockIdx.z;
    const int m0 = blockIdx.y << 7, n0 = blockIdx.x << 7;
    const unsigned short* A = P + ((long)bl * NS + m0) * (2 * NS);
    const unsigned short* B = ZT + (long)bl * (ND * NS) + (long)n0 * NS;
    float* o = outp + ((long)bl * NS + m0) * ND + n0;
    const float* bi = bp + n0;
    gemm_core<1>(A, nullptr, 2 * NS, B, nullptr, NS, NS, [=](int r, int c, float v) {
        float* d = o + (long)r * ND + c;
        if constexpr (MODE == 0) *d = v + bi[c];
        else *d += v;
    });
}

// ---------------------------------------------------------------------------

extern "C" void kernel_launch(void* const* d_in, const int* in_sizes, int n_in,
                              void* d_out, int out_size, void* d_ws, size_t ws_size,
                              hipStream_t stream) {
    (void)in_sizes; (void)n_in; (void)out_size; (void)ws_size;
    const float* x  = (const float*)d_in[0];
    const float* Wq = (const float*)d_in[1];
    const float* bq = (const float*)d_in[2];
    const float* Wk = (const float*)d_in[3];
    const float* bk = (const float*)d_in[4];  (void)bk;  // cancels in softmax
    const float* Wv = (const float*)d_in[5];
    const float* bv = (const float*)d_in[6];
    const float* Wp = (const float*)d_in[7];
    const float* bp = (const float*)d_in[8];

    const size_t nx  = (size_t)NB * NS * ND;   // 6,291,456
    const size_t nw  = (size_t)NH * ND * ND;   // 7,077,888

    char* p = (char*)d_ws;
    auto alloc = [&](size_t bytes) -> void* {
        void* r = (void*)p;
        p += (bytes + 255) & ~(size_t)255;
        return r;
    };
    // persistent
    unsigned short* xh   = (unsigned short*)alloc(nx * 2);        // 12.58 MB
    unsigned short* xl   = (unsigned short*)alloc(nx * 2);
    unsigned short* MTh  = (unsigned short*)alloc(nw * 2);        // 14.16 MB
    unsigned short* MTl  = (unsigned short*)alloc(nw * 2);
    unsigned short* NT   = (unsigned short*)alloc(nw * 2);
    float*          rk   = (float*)alloc((size_t)NH * ND * 4);
    float*          s_all= (float*)alloc((size_t)NH * ND * 4);
    float*          w_all= (float*)alloc((size_t)NH * NB * NS * 4);
    // union region U: phase A = {Wq,Wk splits | Wvb,WpT}; phase B = {G,Sc,ZT}
    char* U = (char*)alloc(2 * nx * 2 + ((size_t)NB * NS * NS * 4) + ((size_t)NB * NS * ND * 2));
    // phase A views
    unsigned short* Wqh = (unsigned short*)U;
    unsigned short* Wql = Wqh + nw;
    unsigned short* Wkh = Wql + nw;
    unsigned short* Wkl = Wkh + nw;
    unsigned short* Wvb = (unsigned short*)U;        // after MT done
    unsigned short* WpT = Wvb + nw;
    // phase B views
    unsigned short* Gh = (unsigned short*)U;
    unsigned short* Gl = Gh + nx;
    float*          Sc = (float*)(Gl + nx);
    unsigned short* ZT = (unsigned short*)(Sc + (size_t)NB * NS * NS);

    // ---------------- setup ----------------
    k_split<<<(int)(nx / 4 / 256), 256, 0, stream>>>(x, xh, xl, (int)(nx / 4));
    k_split<<<(int)(nw / 4 / 256), 256, 0, stream>>>(Wq, Wqh, Wql, (int)(nw / 4));
    k_split<<<(int)(nw / 4 / 256), 256, 0, stream>>>(Wk, Wkh, Wkl, (int)(nw / 4));
    k_MT<<<dim3(6, 6, 12), 256, 0, stream>>>(Wkh, Wkl, Wqh, Wql, MTh, MTl);
    k_rk<<<dim3(192, 12), 256, 0, stream>>>(Wk, bq, rk);
    k_w <<<2048, 256, 0, stream>>>(x, rk, w_all);
    // now Wq/Wk splits are dead -> overlay Wvb/WpT
    k_castbf<<<(int)(nw / 4 / 256), 256, 0, stream>>>(Wv, Wvb, (int)(nw / 4));
    k_transpose<<<dim3(12, 12, 12), 256, 0, stream>>>(Wp, WpT, ND, ND);
    k_NT<<<dim3(6, 6, 12), 256, 0, stream>>>(WpT, Wvb, NT);
    k_sh<<<dim3(192, 12), 256, 0, stream>>>(WpT, bv, s_all);

    // ---------------- per-head pipeline ----------------
    for (int h = 0; h < NH; h++) {
        const long hw = (long)h * ND * ND;
        k_G<<<dim3(6, 64), 256, 0, stream>>>(xh, xl, MTh + hw, MTl + hw, Gh, Gl);
        k_scores<<<dim3(8, 8, 8), 256, 0, stream>>>(Gh, Gl, xh, xl,
                                                    w_all + (long)h * NB * NS, Sc);
        k_softmax<<<2048, 256, 0, stream>>>(Sc);
        k_Z<<<dim3(6, 64), 256, 0, stream>>>(xh, NT + hw, s_all + h * ND, ZT);
        if (h == 0)
            k_PV<0><<<dim3(6, 8, 8), 256, 0, stream>>>((unsigned short*)Sc, ZT, bp,
                                                       (float*)d_out);
        else
            k_PV<1><<<dim3(6, 8, 8), 256, 0, stream>>>((unsigned short*)Sc, ZT, bp,
                                                       (float*)d_out);
    }
}

// Round 7
// 1889.396 us; speedup vs baseline: 5.4193x; 1.0597x over previous
//
#include <hip/hip_runtime.h>

// ---------------------------------------------------------------------------
// MultiHeadAttention (full-width per-head projections), MI355X gfx950.
// Round 7: race isolation. R5/R6's double-buffered stage-before-compute
// gemm_core diverged at replay under BOTH barrier flavors -> the dbuf
// schedule itself is the prime suspect (m152: sync-structure edits race in
// audit-resistant ways). Revert gemm_core VERBATIM to the R4 structure that
// passed replay validation twice (static internal __shared__, single buffer,
// sync -> stage -> sync -> ds_read+MFMA). Keep the launch compaction
// (k_ZSM / k_PVG / k_G0), which contains no new intra-kernel sync.
// Math unchanged:
//   scores = softmax_t( 8*( x M_h x^T + w_t ) ),  M_h = Wq_h Wk_h^T
//   out    = sum_h P_h Z_h + bp,  Z_h = x N_h + bv_h Wp_h,  N_h = Wv_h Wp_h
// 3-term bf16 hi/lo split on the score path; bf16 elsewhere; fp32 softmax.
// ---------------------------------------------------------------------------

typedef __attribute__((ext_vector_type(8))) short bf16x8;
typedef __attribute__((ext_vector_type(4))) float fx4;

#define NB 8
#define NS 1024
#define ND 768
#define NH 12

__device__ __forceinline__ unsigned short f2bf(float x) {
    unsigned int u = __float_as_uint(x);
    u += 0x7fffu + ((u >> 16) & 1u);   // round-to-nearest-even bf16
    return (unsigned short)(u >> 16);
}
__device__ __forceinline__ float bf2f(unsigned short h) {
    return __uint_as_float(((unsigned int)h) << 16);
}

// async global->LDS, 16B per lane; LDS base must be wave-uniform.
__device__ __forceinline__ void gll16(const void* g, void* l) {
    __builtin_amdgcn_global_load_lds(
        (const __attribute__((address_space(1))) void*)g,
        (__attribute__((address_space(3))) void*)l, 16, 0, 0);
}

// ---------------- elementwise: f32 -> bf16 hi + bf16 lo ----------------------
__global__ void k_split(const float* __restrict__ in, unsigned short* __restrict__ hi,
                        unsigned short* __restrict__ lo, int n4) {
    int i = blockIdx.x * 256 + threadIdx.x;
    if (i >= n4) return;
    float4 v = ((const float4*)in)[i];
    ushort4 h, l;
    h.x = f2bf(v.x); l.x = f2bf(v.x - bf2f(h.x));
    h.y = f2bf(v.y); l.y = f2bf(v.y - bf2f(h.y));
    h.z = f2bf(v.z); l.z = f2bf(v.z - bf2f(h.z));
    h.w = f2bf(v.w); l.w = f2bf(v.w - bf2f(h.w));
    ((ushort4*)hi)[i] = h;
    ((ushort4*)lo)[i] = l;
}

// ---------------- elementwise: f32 -> bf16 -----------------------------------
__global__ void k_castbf(const float* __restrict__ in, unsigned short* __restrict__ out,
                         int n4) {
    int i = blockIdx.x * 256 + threadIdx.x;
    if (i >= n4) return;
    float4 v = ((const float4*)in)[i];
    ushort4 h;
    h.x = f2bf(v.x); h.y = f2bf(v.y); h.z = f2bf(v.z); h.w = f2bf(v.w);
    ((ushort4*)out)[i] = h;
}

// ---------------- transpose f32 [z][R][C] -> bf16 [z][C][R] ------------------
__global__ void k_transpose(const float* __restrict__ in, unsigned short* __restrict__ oh,
                            int R, int C) {
    __shared__ float tile[64][65];
    long zo = (long)blockIdx.z * R * C;
    in += zo; oh += zo;
    int c0 = blockIdx.x * 64, r0 = blockIdx.y * 64;
    int tc = threadIdx.x & 63, t4 = threadIdx.x >> 6;
    #pragma unroll
    for (int i = 0; i < 16; i++) {
        int r = (i << 2) + t4;
        tile[r][tc] = in[(long)(r0 + r) * C + c0 + tc];
    }
    __syncthreads();
    #pragma unroll
    for (int i = 0; i < 16; i++) {
        int c = (i << 2) + t4;
        oh[(long)(c0 + c) * R + r0 + tc] = f2bf(tile[tc][c]);
    }
}

// ---- rk[h][d] = sum_e Wk[h,d,e]*bq[h,e]  (wave per (h,d)) -------------------
__global__ __launch_bounds__(256) void k_rk(const float* __restrict__ Wk,
                                            const float* __restrict__ bq,
                                            float* __restrict__ rk) {
    int h = blockIdx.y;
    int d = blockIdx.x * 4 + (threadIdx.x >> 6);
    int lane = threadIdx.x & 63;
    const float4* row = (const float4*)(Wk + ((long)h * ND + d) * ND);
    const float4* bv4 = (const float4*)(bq + h * ND);
    float acc = 0.f;
    #pragma unroll
    for (int i = 0; i < 3; i++) {
        float4 a = row[lane + (i << 6)];
        float4 b = bv4[lane + (i << 6)];
        acc += a.x * b.x + a.y * b.y + a.z * b.z + a.w * b.w;
    }
    #pragma unroll
    for (int o = 32; o > 0; o >>= 1) acc += __shfl_xor(acc, o);
    if (lane == 0) rk[h * ND + d] = acc;
}

// ---- s_all[h][j] = sum_e bv[h,e]*Wp[h*768+e, j] via WpT (wave per (h,j)) ----
__global__ __launch_bounds__(256) void k_sh(const unsigned short* __restrict__ WpT,
                                            const float* __restrict__ bv,
                                            float* __restrict__ s_all) {
    int h = blockIdx.y;
    int j = blockIdx.x * 4 + (threadIdx.x >> 6);
    int lane = threadIdx.x & 63;
    const ushort4* row = (const ushort4*)(WpT + ((long)h * ND + j) * ND);
    const float* bvh = bv + h * ND;
    float acc = 0.f;
    #pragma unroll
    for (int i = 0; i < 3; i++) {
        int c = lane + (i << 6);
        ushort4 u = row[c];
        int e = c << 2;
        acc += bf2f(u.x) * bvh[e] + bf2f(u.y) * bvh[e + 1]
             + bf2f(u.z) * bvh[e + 2] + bf2f(u.w) * bvh[e + 3];
    }
    #pragma unroll
    for (int o = 32; o > 0; o >>= 1) acc += __shfl_xor(acc, o);
    if (lane == 0) s_all[h * ND + j] = acc;
}

// ---- w_all[h][s] = x_s . rk[h]  (wave per row, rk staged in LDS) ------------
__global__ __launch_bounds__(256) void k_w(const float* __restrict__ x,
                                           const float* __restrict__ rk,
                                           float* __restrict__ w_all) {
    __shared__ float srk[NH * ND];
    for (int i = threadIdx.x; i < NH * ND; i += 256) srk[i] = rk[i];
    __syncthreads();
    int row = blockIdx.x * 4 + (threadIdx.x >> 6);
    int lane = threadIdx.x & 63;
    const float4* xr = (const float4*)(x + (long)row * ND);
    float4 xa[3];
    #pragma unroll
    for (int i = 0; i < 3; i++) xa[i] = xr[lane + (i << 6)];
    for (int h = 0; h < NH; h++) {
        const float* r = srk + h * ND;
        float acc = 0.f;
        #pragma unroll
        for (int i = 0; i < 3; i++) {
            int e = (lane + (i << 6)) << 2;
            acc += xa[i].x * r[e] + xa[i].y * r[e + 1]
                 + xa[i].z * r[e + 2] + xa[i].w * r[e + 3];
        }
        #pragma unroll
        for (int o = 32; o > 0; o >>= 1) acc += __shfl_xor(acc, o);
        if (lane == 0) w_all[h * (NB * NS) + row] = acc;
    }
}

// ---------------------------------------------------------------------------
// MFMA GEMM core — VERBATIM round-4 structure (passed replay validation 2x):
// 128x128 tile, BK=32, 4 waves (2x2), single-buffer, per K-tile:
//   __syncthreads -> stage (global_load_lds x8) -> __syncthreads -> ds+MFMA.
// global_load_lds with inverse-swizzled global source (chunk ^= (row>>1)&3),
// linear LDS dest, swizzled ds_read -> 0 bank conflicts (verified round 4).
// C/D layout (HW-verified): col = lane&15, row = (lane>>4)*4 + reg.
// ---------------------------------------------------------------------------
template<int NTERMS, class Epi>
__device__ __forceinline__ void gemm_core(
    const unsigned short* __restrict__ Ah, const unsigned short* __restrict__ Al, int lda,
    const unsigned short* __restrict__ Bh, const unsigned short* __restrict__ Bl, int ldb,
    int K, Epi epi)
{
    constexpr int NT = (NTERMS == 3) ? 4 : 2;
    __shared__ __align__(16) unsigned short sm[NT][4096];   // 8KB per tile

    const int t = threadIdx.x;
    const int lane = t & 63;
    const int w = t >> 6;
    const int wm = (w >> 1) << 6;
    const int wn = (w & 1) << 6;
    const int lr = lane & 15;
    const int lg = lane >> 4;

    // staging: lane covers row w*32 + (lane>>2) (+16 for 2nd instr),
    // global 16B chunk index = (lane&3) ^ ((row>>1)&3); LDS dest linear.
    const int srA = (w << 5) + (lane >> 2);
    const int swz = (srA >> 1) & 3;
    const int skb = (((lane & 3) ^ swz) << 4);
    const int ldso = w << 11;                // wave-uniform LDS byte offset

    const long ga0 = (long)srA * lda * 2 + skb;
    const long ga1 = ga0 + (long)lda * 32;   // +16 rows (bytes)
    const long gb0 = (long)srA * ldb * 2 + skb;
    const long gb1 = gb0 + (long)ldb * 32;

    const char* pAh = (const char*)Ah;
    const char* pBh = (const char*)Bh;
    const char* pAl = (const char*)Al;
    const char* pBl = (const char*)Bl;
    char* smA = (char*)&sm[0][0];
    char* smB = (char*)&sm[1][0];
    char* smA2 = (char*)&sm[NT - 2][0];
    char* smB2 = (char*)&sm[NT - 1][0];

    int offA[4], offB[4];
    #pragma unroll
    for (int i = 0; i < 4; i++) {
        int ra = wm + (i << 4) + lr;
        offA[i] = ra * 32 + ((lg ^ ((ra >> 1) & 3)) << 3);   // ushort index
        int rb = wn + (i << 4) + lr;
        offB[i] = rb * 32 + ((lg ^ ((rb >> 1) & 3)) << 3);
    }

    fx4 acc[4][4] = {};

    for (int k0 = 0; k0 < K; k0 += 32) {
        const long kb2 = (long)k0 * 2;
        __syncthreads();
        gll16(pAh + ga0 + kb2, smA + ldso);
        gll16(pAh + ga1 + kb2, smA + ldso + 1024);
        gll16(pBh + gb0 + kb2, smB + ldso);
        gll16(pBh + gb1 + kb2, smB + ldso + 1024);
        if constexpr (NTERMS == 3) {
            gll16(pAl + ga0 + kb2, smA2 + ldso);
            gll16(pAl + ga1 + kb2, smA2 + ldso + 1024);
            gll16(pBl + gb0 + kb2, smB2 + ldso);
            gll16(pBl + gb1 + kb2, smB2 + ldso + 1024);
        }
        __syncthreads();

        bf16x8 fa[4], fb[4], fa2[4], fb2[4];
        #pragma unroll
        for (int i = 0; i < 4; i++) {
            fa[i] = *(const bf16x8*)&sm[0][offA[i]];
            fb[i] = *(const bf16x8*)&sm[1][offB[i]];
        }
        if constexpr (NTERMS == 3) {
            #pragma unroll
            for (int i = 0; i < 4; i++) {
                fa2[i] = *(const bf16x8*)&sm[2][offA[i]];
                fb2[i] = *(const bf16x8*)&sm[3][offB[i]];
            }
        }
        #pragma unroll
        for (int i = 0; i < 4; i++)
            #pragma unroll
            for (int j = 0; j < 4; j++) {
                acc[i][j] = __builtin_amdgcn_mfma_f32_16x16x32_bf16(fa[i], fb[j], acc[i][j], 0, 0, 0);
                if constexpr (NTERMS == 3) {
                    acc[i][j] = __builtin_amdgcn_mfma_f32_16x16x32_bf16(fa[i], fb2[j], acc[i][j], 0, 0, 0);
                    acc[i][j] = __builtin_amdgcn_mfma_f32_16x16x32_bf16(fa2[i], fb[j], acc[i][j], 0, 0, 0);
                }
            }
    }

    #pragma unroll
    for (int i = 0; i < 4; i++)
        #pragma unroll
        for (int j = 0; j < 4; j++)
            #pragma unroll
            for (int r = 0; r < 4; r++)
                epi(wm + (i << 4) + (lg << 2) + r, wn + (j << 4) + lr, acc[i][j][r]);
}

// ---------------- softmax body (wave per row, 4 rows per block) --------------
__device__ __forceinline__ void softmax_rows(float* __restrict__ Sc, int blk) {
    int row = blk * 4 + ((int)threadIdx.x >> 6);
    int lane = threadIdx.x & 63;
    float* rp = Sc + (long)row * NS;
    const float4* src = (const float4*)rp + (lane << 2);
    float v[16];
    #pragma unroll
    for (int i = 0; i < 4; i++) {
        float4 a = src[i];
        v[i * 4 + 0] = a.x; v[i * 4 + 1] = a.y; v[i * 4 + 2] = a.z; v[i * 4 + 3] = a.w;
    }
    float m = v[0];
    #pragma unroll
    for (int i = 1; i < 16; i++) m = fmaxf(m, v[i]);
    #pragma unroll
    for (int o = 32; o > 0; o >>= 1) m = fmaxf(m, __shfl_xor(m, o));
    float s = 0.f, p[16];
    #pragma unroll
    for (int i = 0; i < 16; i++) { p[i] = __expf((v[i] - m) * 8.0f); s += p[i]; }
    #pragma unroll
    for (int o = 32; o > 0; o >>= 1) s += __shfl_xor(s, o);
    float inv = 1.0f / s;
    unsigned int wrd[8];
    #pragma unroll
    for (int i = 0; i < 8; i++) {
        unsigned int u0 = f2bf(p[2 * i] * inv);
        unsigned int u1 = f2bf(p[2 * i + 1] * inv);
        wrd[i] = u0 | (u1 << 16);
    }
    uint4* dst = (uint4*)((unsigned short*)rp + (lane << 4));
    dst[0] = make_uint4(wrd[0], wrd[1], wrd[2], wrd[3]);
    dst[1] = make_uint4(wrd[4], wrd[5], wrd[6], wrd[7]);
}

// ------------------------- GEMM wrapper kernels ------------------------------

// MT_h[r,c] = sum_e Wk_h[r,e]*Wq_h[c,e], split out. grid (6,6,12) 3-term.
__global__ __launch_bounds__(256, 2) void k_MT(
    const unsigned short* __restrict__ Wkh, const unsigned short* __restrict__ Wkl,
    const unsigned short* __restrict__ Wqh, const unsigned short* __restrict__ Wql,
    unsigned short* __restrict__ MTh, unsigned short* __restrict__ MTl)
{
    const long hw = (long)blockIdx.z * (ND * ND);
    const int m0 = blockIdx.y << 7, n0 = blockIdx.x << 7;
    unsigned short* oh = MTh + hw + (long)m0 * ND + n0;
    unsigned short* ol = MTl + hw + (long)m0 * ND + n0;
    gemm_core<3>(Wkh + hw + (long)m0 * ND, Wkl + hw + (long)m0 * ND, ND,
                 Wqh + hw + (long)n0 * ND, Wql + hw + (long)n0 * ND, ND, ND,
                 [=](int r, int c, float v) {
                     unsigned short hh = f2bf(v);
                     oh[r * ND + c] = hh;
                     ol[r * ND + c] = f2bf(v - bf2f(hh));
                 });
}

// NT_h[r=j,c=d] = sum_e WpT_h[j,e]*Wv_h[d,e], bf16 out. grid (6,6,12) 1-term.
__global__ __launch_bounds__(256, 2) void k_NT(
    const unsigned short* __restrict__ WpT, const unsigned short* __restrict__ Wvb,
    unsigned short* __restrict__ NTo)
{
    const long hw = (long)blockIdx.z * (ND * ND);
    const int m0 = blockIdx.y << 7, n0 = blockIdx.x << 7;
    unsigned short* o = NTo + hw + (long)m0 * ND + n0;
    gemm_core<1>(WpT + hw + (long)m0 * ND, nullptr, ND,
                 Wvb + hw + (long)n0 * ND, nullptr, ND, ND,
                 [=](int r, int c, float v) { o[r * ND + c] = f2bf(v); });
}

// G = x * M_h (split out), head 0 bootstrap. grid (6,64) 3-term.
__global__ __launch_bounds__(256, 2) void k_G0(
    const unsigned short* __restrict__ xh, const unsigned short* __restrict__ xl,
    const unsigned short* __restrict__ MTh, const unsigned short* __restrict__ MTl,
    unsigned short* __restrict__ Gh, unsigned short* __restrict__ Gl)
{
    const int m0 = blockIdx.y << 7, n0 = blockIdx.x << 7;
    unsigned short* oh = Gh + (long)m0 * ND + n0;
    unsigned short* ol = Gl + (long)m0 * ND + n0;
    gemm_core<3>(xh + (long)m0 * ND, xl + (long)m0 * ND, ND,
                 MTh + (long)n0 * ND, MTl + (long)n0 * ND, ND, ND,
                 [=](int r, int c, float v) {
                     unsigned short hh = f2bf(v);
                     oh[(long)r * ND + c] = hh;
                     ol[(long)r * ND + c] = f2bf(v - bf2f(hh));
                 });
}

// scores[bl][s][t] = G_s . x_t + w[t]  (fp32, unscaled). grid (8,8,8) 3-term.
__global__ __launch_bounds__(256, 2) void k_scores(
    const unsigned short* __restrict__ Gh, const unsigned short* __restrict__ Gl,
    const unsigned short* __restrict__ xh, const unsigned short* __restrict__ xl,
    const float* __restrict__ wv, float* __restrict__ Sc)
{
    const int bl = blockIdx.z;
    const int m0 = blockIdx.y << 7, n0 = blockIdx.x << 7;
    const long ao = ((long)bl * NS + m0) * ND;
    const long bo = ((long)bl * NS + n0) * ND;
    const float* ww = wv + bl * NS + n0;
    float* out = Sc + ((long)bl * NS + m0) * NS + n0;
    gemm_core<3>(Gh + ao, Gl + ao, ND, xh + bo, xl + bo, ND, ND,
                 [=](int r, int c, float v) { out[(long)r * NS + c] = v + ww[c]; });
}

// fused: blocks [0,384) Z = x*NT_h + s_h -> ZT ; blocks [384,2432) softmax.
__global__ __launch_bounds__(256, 2) void k_ZSM(
    const unsigned short* __restrict__ xh, const unsigned short* __restrict__ NTh,
    const float* __restrict__ sh, unsigned short* __restrict__ ZT,
    float* __restrict__ Sc)
{
    const int bx = blockIdx.x;
    if (bx < 384) {
        const int m0 = (bx / 6) << 7, n0 = (bx % 6) << 7;
        const int bl = m0 >> 10;
        const int s0 = m0 & (NS - 1);
        unsigned short* zt = ZT + (long)bl * (ND * NS);
        gemm_core<1>(xh + (long)m0 * ND, nullptr, ND,
                     NTh + (long)n0 * ND, nullptr, ND, ND,
                     [=](int r, int c, float v) {
                         zt[(long)(n0 + c) * NS + s0 + r] = f2bf(v + sh[n0 + c]);
                     });
    } else {
        softmax_rows(Sc, bx - 384);
    }
}

// fused: blocks [0,384) out += P*Z (fp32 acc in d_out); blocks [384,768)
// G(next head) = x * M_{h+1}. MODE 0: first head (write + bias), else +=.
template<int MODE>
__global__ __launch_bounds__(256, 2) void k_PVG(
    const unsigned short* __restrict__ P, const unsigned short* __restrict__ ZT,
    const float* __restrict__ bp, float* __restrict__ outp,
    const unsigned short* __restrict__ xh, const unsigned short* __restrict__ xl,
    const unsigned short* __restrict__ MTh, const unsigned short* __restrict__ MTl,
    unsigned short* __restrict__ Gh, unsigned short* __restrict__ Gl)
{
    const int bx = blockIdx.x;
    if (bx < 384) {
        const int bl = bx / 48;
        const int rr = bx % 48;
        const int m0 = (rr / 6) << 7, n0 = (rr % 6) << 7;
        const unsigned short* A = P + ((long)bl * NS + m0) * (2 * NS);
        const unsigned short* B = ZT + (long)bl * (ND * NS) + (long)n0 * NS;
        float* o = outp + ((long)bl * NS + m0) * ND + n0;
        const float* bi = bp + n0;
        gemm_core<1>(A, nullptr, 2 * NS, B, nullptr, NS, NS,
                     [=](int r, int c, float v) {
                         float* d = o + (long)r * ND + c;
                         if constexpr (MODE == 0) *d = v + bi[c];
                         else *d += v;
                     });
    } else {
        const int g = bx - 384;
        const int m0 = (g / 6) << 7, n0 = (g % 6) << 7;
        unsigned short* oh = Gh + (long)m0 * ND + n0;
        unsigned short* ol = Gl + (long)m0 * ND + n0;
        gemm_core<3>(xh + (long)m0 * ND, xl + (long)m0 * ND, ND,
                     MTh + (long)n0 * ND, MTl + (long)n0 * ND, ND, ND,
                     [=](int r, int c, float v) {
                         unsigned short hh = f2bf(v);
                         oh[(long)r * ND + c] = hh;
                         ol[(long)r * ND + c] = f2bf(v - bf2f(hh));
                     });
    }
}

// ---------------------------------------------------------------------------

extern "C" void kernel_launch(void* const* d_in, const int* in_sizes, int n_in,
                              void* d_out, int out_size, void* d_ws, size_t ws_size,
                              hipStream_t stream) {
    (void)in_sizes; (void)n_in; (void)out_size; (void)ws_size;
    const float* x  = (const float*)d_in[0];
    const float* Wq = (const float*)d_in[1];
    const float* bq = (const float*)d_in[2];
    const float* Wk = (const float*)d_in[3];
    const float* bk = (const float*)d_in[4];  (void)bk;  // cancels in softmax
    const float* Wv = (const float*)d_in[5];
    const float* bv = (const float*)d_in[6];
    const float* Wp = (const float*)d_in[7];
    const float* bp = (const float*)d_in[8];

    const size_t nx  = (size_t)NB * NS * ND;   // 6,291,456
    const size_t nw  = (size_t)NH * ND * ND;   // 7,077,888

    char* p = (char*)d_ws;
    auto alloc = [&](size_t bytes) -> void* {
        void* r = (void*)p;
        p += (bytes + 255) & ~(size_t)255;
        return r;
    };
    // persistent
    unsigned short* xh   = (unsigned short*)alloc(nx * 2);
    unsigned short* xl   = (unsigned short*)alloc(nx * 2);
    unsigned short* MTh  = (unsigned short*)alloc(nw * 2);
    unsigned short* MTl  = (unsigned short*)alloc(nw * 2);
    unsigned short* NTb  = (unsigned short*)alloc(nw * 2);
    float*          rk   = (float*)alloc((size_t)NH * ND * 4);
    float*          s_all= (float*)alloc((size_t)NH * ND * 4);
    float*          w_all= (float*)alloc((size_t)NH * NB * NS * 4);
    // union region U: phase A = {Wq,Wk splits | Wvb,WpT}; phase B = {G,Sc,ZT}
    char* U = (char*)alloc(2 * nx * 2 + ((size_t)NB * NS * NS * 4) + ((size_t)NB * NS * ND * 2));
    // phase A views
    unsigned short* Wqh = (unsigned short*)U;
    unsigned short* Wql = Wqh + nw;
    unsigned short* Wkh = Wql + nw;
    unsigned short* Wkl = Wkh + nw;
    unsigned short* Wvb = (unsigned short*)U;        // after MT done
    unsigned short* WpT = Wvb + nw;
    // phase B views
    unsigned short* Gh = (unsigned short*)U;
    unsigned short* Gl = Gh + nx;
    float*          Sc = (float*)(Gl + nx);
    unsigned short* ZT = (unsigned short*)(Sc + (size_t)NB * NS * NS);

    // ---------------- setup ----------------
    k_split<<<(int)(nx / 4 / 256), 256, 0, stream>>>(x, xh, xl, (int)(nx / 4));
    k_split<<<(int)(nw / 4 / 256), 256, 0, stream>>>(Wq, Wqh, Wql, (int)(nw / 4));
    k_split<<<(int)(nw / 4 / 256), 256, 0, stream>>>(Wk, Wkh, Wkl, (int)(nw / 4));
    k_MT<<<dim3(6, 6, 12), 256, 0, stream>>>(Wkh, Wkl, Wqh, Wql, MTh, MTl);
    k_rk<<<dim3(192, 12), 256, 0, stream>>>(Wk, bq, rk);
    k_w <<<2048, 256, 0, stream>>>(x, rk, w_all);
    // now Wq/Wk splits are dead -> overlay Wvb/WpT
    k_castbf<<<(int)(nw / 4 / 256), 256, 0, stream>>>(Wv, Wvb, (int)(nw / 4));
    k_transpose<<<dim3(12, 12, 12), 256, 0, stream>>>(Wp, WpT, ND, ND);
    k_NT<<<dim3(6, 6, 12), 256, 0, stream>>>(WpT, Wvb, NTb);
    k_sh<<<dim3(192, 12), 256, 0, stream>>>(WpT, bv, s_all);

    // ---------------- per-head pipeline ----------------
    k_G0<<<dim3(6, 64), 256, 0, stream>>>(xh, xl, MTh, MTl, Gh, Gl);
    for (int h = 0; h < NH; h++) {
        const long hwn = (long)(h + 1) * ND * ND;   // next head's M
        k_scores<<<dim3(8, 8, 8), 256, 0, stream>>>(Gh, Gl, xh, xl,
                                                    w_all + (long)h * NB * NS, Sc);
        k_ZSM<<<2432, 256, 0, stream>>>(xh, NTb + (long)h * ND * ND,
                                        s_all + h * ND, ZT, Sc);
        const int ng = (h + 1 < NH) ? 768 : 384;
        if (h == 0)
            k_PVG<0><<<ng, 256, 0, stream>>>((unsigned short*)Sc, ZT, bp, (float*)d_out,
                                             xh, xl, MTh + hwn, MTl + hwn, Gh, Gl);
        else
            k_PVG<1><<<ng, 256, 0, stream>>>((unsigned short*)Sc, ZT, bp, (float*)d_out,
                                             xh, xl,
                                             MTh + ((h + 1 < NH) ? hwn : 0),
                                             MTl + ((h + 1 < NH) ? hwn : 0), Gh, Gl);
    }
}

// Round 8
// 1493.979 us; speedup vs baseline: 6.8536x; 1.2647x over previous
//
#include <hip/hip_runtime.h>

// ---------------------------------------------------------------------------
// MultiHeadAttention (full-width per-head projections), MI355X gfx950.
// Round 8: L2/XCD-aware block remapping (pure index math; xcd = bid&7 pins
// the operand panel that fits a 4MB XCD L2), single shared-LDS buffer per
// kernel (k_PVG 48->32KB => 4 blocks/CU by VGPR), setup fused 10->4 launches.
// gemm_core sync schedule is BYTE-IDENTICAL to the twice-replay-verified
// R4/R7 structure (single buffer, sync -> stage -> sync -> ds+MFMA).
// Math unchanged:
//   scores = softmax_t( 8*( x M_h x^T + w_t ) ),  M_h = Wq_h Wk_h^T
//   out    = sum_h P_h Z_h + bp,  Z_h = x N_h + bv_h Wp_h,  N_h = Wv_h Wp_h
// 3-term bf16 hi/lo split on the score path; bf16 elsewhere; fp32 softmax.
// ---------------------------------------------------------------------------

typedef __attribute__((ext_vector_type(8))) short bf16x8;
typedef __attribute__((ext_vector_type(4))) float fx4;

#define NB 8
#define NS 1024
#define ND 768
#define NH 12

__device__ __forceinline__ unsigned short f2bf(float x) {
    unsigned int u = __float_as_uint(x);
    u += 0x7fffu + ((u >> 16) & 1u);   // round-to-nearest-even bf16
    return (unsigned short)(u >> 16);
}
__device__ __forceinline__ float bf2f(unsigned short h) {
    return __uint_as_float(((unsigned int)h) << 16);
}

// async global->LDS, 16B per lane; LDS base must be wave-uniform.
__device__ __forceinline__ void gll16(const void* g, void* l) {
    __builtin_amdgcn_global_load_lds(
        (const __attribute__((address_space(1))) void*)g,
        (__attribute__((address_space(3))) void*)l, 16, 0, 0);
}

// ---------------- elementwise bodies ----------------------------------------
__device__ __forceinline__ void split_body(const float* __restrict__ in,
                                           unsigned short* __restrict__ hi,
                                           unsigned short* __restrict__ lo, int i) {
    float4 v = ((const float4*)in)[i];
    ushort4 h, l;
    h.x = f2bf(v.x); l.x = f2bf(v.x - bf2f(h.x));
    h.y = f2bf(v.y); l.y = f2bf(v.y - bf2f(h.y));
    h.z = f2bf(v.z); l.z = f2bf(v.z - bf2f(h.z));
    h.w = f2bf(v.w); l.w = f2bf(v.w - bf2f(h.w));
    ((ushort4*)hi)[i] = h;
    ((ushort4*)lo)[i] = l;
}

// ---------------------------------------------------------------------------
// MFMA GEMM core — schedule VERBATIM from round-4/7 (replay-verified):
// 128x128 tile, BK=32, 4 waves (2x2), single-buffer, per K-tile:
//   __syncthreads -> stage (global_load_lds x8) -> __syncthreads -> ds+MFMA.
// Only change: LDS comes from the caller (one array per kernel) instead of
// per-instantiation static arrays. Layout: A @0, B @8KB, A2 @16KB, B2 @24KB.
// global_load_lds inverse-swizzled source (chunk ^= (row>>1)&3), linear LDS
// dest, swizzled ds_read -> 0 bank conflicts (verified round 4).
// C/D layout (HW-verified): col = lane&15, row = (lane>>4)*4 + reg.
// ---------------------------------------------------------------------------
template<int NTERMS, class Epi>
__device__ __forceinline__ void gemm_core(
    char* __restrict__ smem,
    const unsigned short* __restrict__ Ah, const unsigned short* __restrict__ Al, int lda,
    const unsigned short* __restrict__ Bh, const unsigned short* __restrict__ Bl, int ldb,
    int K, Epi epi)
{
    const int t = threadIdx.x;
    const int lane = t & 63;
    const int w = t >> 6;
    const int wm = (w >> 1) << 6;
    const int wn = (w & 1) << 6;
    const int lr = lane & 15;
    const int lg = lane >> 4;

    const int srA = (w << 5) + (lane >> 2);
    const int swz = (srA >> 1) & 3;
    const int skb = (((lane & 3) ^ swz) << 4);
    const int ldso = w << 11;                // wave-uniform LDS byte offset

    const long ga0 = (long)srA * lda * 2 + skb;
    const long ga1 = ga0 + (long)lda * 32;   // +16 rows (bytes)
    const long gb0 = (long)srA * ldb * 2 + skb;
    const long gb1 = gb0 + (long)ldb * 32;

    const char* pAh = (const char*)Ah;
    const char* pBh = (const char*)Bh;
    const char* pAl = (const char*)Al;
    const char* pBl = (const char*)Bl;
    char* smA  = smem;
    char* smB  = smem + 8192;
    char* smA2 = smem + ((NTERMS == 3) ? 16384 : 0);
    char* smB2 = smem + ((NTERMS == 3) ? 24576 : 8192);

    int offA[4], offB[4];
    #pragma unroll
    for (int i = 0; i < 4; i++) {
        int ra = wm + (i << 4) + lr;
        offA[i] = ra * 32 + ((lg ^ ((ra >> 1) & 3)) << 3);   // ushort index
        int rb = wn + (i << 4) + lr;
        offB[i] = rb * 32 + ((lg ^ ((rb >> 1) & 3)) << 3);
    }

    fx4 acc[4][4] = {};

    for (int k0 = 0; k0 < K; k0 += 32) {
        const long kb2 = (long)k0 * 2;
        __syncthreads();
        gll16(pAh + ga0 + kb2, smA + ldso);
        gll16(pAh + ga1 + kb2, smA + ldso + 1024);
        gll16(pBh + gb0 + kb2, smB + ldso);
        gll16(pBh + gb1 + kb2, smB + ldso + 1024);
        if constexpr (NTERMS == 3) {
            gll16(pAl + ga0 + kb2, smA2 + ldso);
            gll16(pAl + ga1 + kb2, smA2 + ldso + 1024);
            gll16(pBl + gb0 + kb2, smB2 + ldso);
            gll16(pBl + gb1 + kb2, smB2 + ldso + 1024);
        }
        __syncthreads();

        bf16x8 fa[4], fb[4], fa2[4], fb2[4];
        #pragma unroll
        for (int i = 0; i < 4; i++) {
            fa[i] = *(const bf16x8*)((const unsigned short*)smA + offA[i]);
            fb[i] = *(const bf16x8*)((const unsigned short*)smB + offB[i]);
        }
        if constexpr (NTERMS == 3) {
            #pragma unroll
            for (int i = 0; i < 4; i++) {
                fa2[i] = *(const bf16x8*)((const unsigned short*)smA2 + offA[i]);
                fb2[i] = *(const bf16x8*)((const unsigned short*)smB2 + offB[i]);
            }
        }
        #pragma unroll
        for (int i = 0; i < 4; i++)
            #pragma unroll
            for (int j = 0; j < 4; j++) {
                acc[i][j] = __builtin_amdgcn_mfma_f32_16x16x32_bf16(fa[i], fb[j], acc[i][j], 0, 0, 0);
                if constexpr (NTERMS == 3) {
                    acc[i][j] = __builtin_amdgcn_mfma_f32_16x16x32_bf16(fa[i], fb2[j], acc[i][j], 0, 0, 0);
                    acc[i][j] = __builtin_amdgcn_mfma_f32_16x16x32_bf16(fa2[i], fb[j], acc[i][j], 0, 0, 0);
                }
            }
    }

    #pragma unroll
    for (int i = 0; i < 4; i++)
        #pragma unroll
        for (int j = 0; j < 4; j++)
            #pragma unroll
            for (int r = 0; r < 4; r++)
                epi(wm + (i << 4) + (lg << 2) + r, wn + (j << 4) + lr, acc[i][j][r]);
}

// ---------------- softmax body (wave per row, 4 rows per block) --------------
__device__ __forceinline__ void softmax_rows(float* __restrict__ Sc, int blk) {
    int row = blk * 4 + ((int)threadIdx.x >> 6);
    int lane = threadIdx.x & 63;
    float* rp = Sc + (long)row * NS;
    const float4* src = (const float4*)rp + (lane << 2);
    float v[16];
    #pragma unroll
    for (int i = 0; i < 4; i++) {
        float4 a = src[i];
        v[i * 4 + 0] = a.x; v[i * 4 + 1] = a.y; v[i * 4 + 2] = a.z; v[i * 4 + 3] = a.w;
    }
    float m = v[0];
    #pragma unroll
    for (int i = 1; i < 16; i++) m = fmaxf(m, v[i]);
    #pragma unroll
    for (int o = 32; o > 0; o >>= 1) m = fmaxf(m, __shfl_xor(m, o));
    float s = 0.f, p[16];
    #pragma unroll
    for (int i = 0; i < 16; i++) { p[i] = __expf((v[i] - m) * 8.0f); s += p[i]; }
    #pragma unroll
    for (int o = 32; o > 0; o >>= 1) s += __shfl_xor(s, o);
    float inv = 1.0f / s;
    unsigned int wrd[8];
    #pragma unroll
    for (int i = 0; i < 8; i++) {
        unsigned int u0 = f2bf(p[2 * i] * inv);
        unsigned int u1 = f2bf(p[2 * i + 1] * inv);
        wrd[i] = u0 | (u1 << 16);
    }
    uint4* dst = (uint4*)((unsigned short*)rp + (lane << 4));
    dst[0] = make_uint4(wrd[0], wrd[1], wrd[2], wrd[3]);
    dst[1] = make_uint4(wrd[4], wrd[5], wrd[6], wrd[7]);
}

// ------------------------- fused setup kernels -------------------------------
// setup1: split x (6144) | split Wq (6912) | split Wk (6912) | rk (2304).
__global__ void k_setup1(
    const float* __restrict__ x, unsigned short* __restrict__ xh, unsigned short* __restrict__ xl,
    const float* __restrict__ Wq, unsigned short* __restrict__ Wqh, unsigned short* __restrict__ Wql,
    const float* __restrict__ Wk, unsigned short* __restrict__ Wkh, unsigned short* __restrict__ Wkl,
    const float* __restrict__ bq, float* __restrict__ rk)
{
    const int bx = blockIdx.x;
    if (bx < 6144) {
        split_body(x, xh, xl, bx * 256 + threadIdx.x);
    } else if (bx < 13056) {
        split_body(Wq, Wqh, Wql, (bx - 6144) * 256 + threadIdx.x);
    } else if (bx < 19968) {
        split_body(Wk, Wkh, Wkl, (bx - 13056) * 256 + threadIdx.x);
    } else {
        const int idx = bx - 19968;            // [0,2304)
        const int h = idx / 192;
        const int d = (idx % 192) * 4 + ((int)threadIdx.x >> 6);
        const int lane = threadIdx.x & 63;
        const float4* row = (const float4*)(Wk + ((long)h * ND + d) * ND);
        const float4* bv4 = (const float4*)(bq + h * ND);
        float acc = 0.f;
        #pragma unroll
        for (int i = 0; i < 3; i++) {
            float4 a = row[lane + (i << 6)];
            float4 b = bv4[lane + (i << 6)];
            acc += a.x * b.x + a.y * b.y + a.z * b.z + a.w * b.w;
        }
        #pragma unroll
        for (int o = 32; o > 0; o >>= 1) acc += __shfl_xor(acc, o);
        if (lane == 0) rk[h * ND + d] = acc;
    }
}

// setup2: k_MT (432, 3-term gemm) | k_w (2048).
__global__ __launch_bounds__(256, 2) void k_setup2(
    const unsigned short* __restrict__ Wkh, const unsigned short* __restrict__ Wkl,
    const unsigned short* __restrict__ Wqh, const unsigned short* __restrict__ Wql,
    unsigned short* __restrict__ MTh, unsigned short* __restrict__ MTl,
    const float* __restrict__ x, const float* __restrict__ rk, float* __restrict__ w_all)
{
    __shared__ __align__(16) char smem[36864];   // 32KB gemm | 36KB srk
    const int bx = blockIdx.x;
    if (bx < 432) {
        const int n0 = (bx % 6) << 7;
        const int m0 = ((bx / 6) % 6) << 7;
        const long hw = (long)(bx / 36) * (ND * ND);
        unsigned short* oh = MTh + hw + (long)m0 * ND + n0;
        unsigned short* ol = MTl + hw + (long)m0 * ND + n0;
        gemm_core<3>(smem, Wkh + hw + (long)m0 * ND, Wkl + hw + (long)m0 * ND, ND,
                     Wqh + hw + (long)n0 * ND, Wql + hw + (long)n0 * ND, ND, ND,
                     [=](int r, int c, float v) {
                         unsigned short hh = f2bf(v);
                         oh[r * ND + c] = hh;
                         ol[r * ND + c] = f2bf(v - bf2f(hh));
                     });
    } else {
        float* srk = (float*)smem;               // 9216 floats = 36KB
        for (int i = threadIdx.x; i < NH * ND; i += 256) srk[i] = rk[i];
        __syncthreads();
        const int row = (bx - 432) * 4 + ((int)threadIdx.x >> 6);
        const int lane = threadIdx.x & 63;
        const float4* xr = (const float4*)(x + (long)row * ND);
        float4 xa[3];
        #pragma unroll
        for (int i = 0; i < 3; i++) xa[i] = xr[lane + (i << 6)];
        for (int h = 0; h < NH; h++) {
            const float* r = srk + h * ND;
            float acc = 0.f;
            #pragma unroll
            for (int i = 0; i < 3; i++) {
                int e = (lane + (i << 6)) << 2;
                acc += xa[i].x * r[e] + xa[i].y * r[e + 1]
                     + xa[i].z * r[e + 2] + xa[i].w * r[e + 3];
            }
            #pragma unroll
            for (int o = 32; o > 0; o >>= 1) acc += __shfl_xor(acc, o);
            if (lane == 0) w_all[h * (NB * NS) + row] = acc;
        }
    }
}

// setup3 (after MT consumed Wq/Wk splits): castbf Wv (6912) | transpose Wp (1728).
__global__ void k_setup3(const float* __restrict__ Wv, unsigned short* __restrict__ Wvb,
                         const float* __restrict__ Wp, unsigned short* __restrict__ WpT)
{
    __shared__ float tile[64][65];
    const int bx = blockIdx.x;
    if (bx < 6912) {
        int i = bx * 256 + threadIdx.x;
        float4 v = ((const float4*)Wv)[i];
        ushort4 h;
        h.x = f2bf(v.x); h.y = f2bf(v.y); h.z = f2bf(v.z); h.w = f2bf(v.w);
        ((ushort4*)Wvb)[i] = h;
    } else {
        const int idx = bx - 6912;             // [0,1728)
        const int c0 = (idx % 12) * 64;
        const int r0 = ((idx / 12) % 12) * 64;
        const long zo = (long)(idx / 144) * (ND * ND);
        const float* in = Wp + zo;
        unsigned short* oh = WpT + zo;
        const int tc = threadIdx.x & 63, t4 = threadIdx.x >> 6;
        #pragma unroll
        for (int i = 0; i < 16; i++) {
            int r = (i << 2) + t4;
            tile[r][tc] = in[(long)(r0 + r) * ND + c0 + tc];
        }
        __syncthreads();
        #pragma unroll
        for (int i = 0; i < 16; i++) {
            int c = (i << 2) + t4;
            oh[(long)(c0 + c) * ND + r0 + tc] = f2bf(tile[tc][c]);
        }
    }
}

// setup4: k_NT (432, 1-term gemm) | k_sh (2304).
__global__ __launch_bounds__(256, 2) void k_setup4(
    const unsigned short* __restrict__ WpT, const unsigned short* __restrict__ Wvb,
    unsigned short* __restrict__ NTo, const float* __restrict__ bv,
    float* __restrict__ s_all)
{
    __shared__ __align__(16) char smem[16384];
    const int bx = blockIdx.x;
    if (bx < 432) {
        const int n0 = (bx % 6) << 7;
        const int m0 = ((bx / 6) % 6) << 7;
        const long hw = (long)(bx / 36) * (ND * ND);
        unsigned short* o = NTo + hw + (long)m0 * ND + n0;
        gemm_core<1>(smem, WpT + hw + (long)m0 * ND, nullptr, ND,
                     Wvb + hw + (long)n0 * ND, nullptr, ND, ND,
                     [=](int r, int c, float v) { o[r * ND + c] = f2bf(v); });
    } else {
        const int idx = bx - 432;              // [0,2304)
        const int h = idx / 192;
        const int j = (idx % 192) * 4 + ((int)threadIdx.x >> 6);
        const int lane = threadIdx.x & 63;
        const ushort4* row = (const ushort4*)(WpT + ((long)h * ND + j) * ND);
        const float* bvh = bv + h * ND;
        float acc = 0.f;
        #pragma unroll
        for (int i = 0; i < 3; i++) {
            int c = lane + (i << 6);
            ushort4 u = row[c];
            int e = c << 2;
            acc += bf2f(u.x) * bvh[e] + bf2f(u.y) * bvh[e + 1]
                 + bf2f(u.z) * bvh[e + 2] + bf2f(u.w) * bvh[e + 3];
        }
        #pragma unroll
        for (int o = 32; o > 0; o >>= 1) acc += __shfl_xor(acc, o);
        if (lane == 0) s_all[h * ND + j] = acc;
    }
}

// ------------------------- per-head kernels (XCD-remapped) -------------------

// G = x * M_h (split out), head-0 bootstrap. flat grid 384.
// xcd = bx&7 owns m-band [xcd*8, xcd*8+8); n cycles fastest (MT resident/XCD).
__global__ __launch_bounds__(256, 2) void k_G0(
    const unsigned short* __restrict__ xh, const unsigned short* __restrict__ xl,
    const unsigned short* __restrict__ MTh, const unsigned short* __restrict__ MTl,
    unsigned short* __restrict__ Gh, unsigned short* __restrict__ Gl)
{
    __shared__ __align__(16) char smem[32768];
    const int bx = blockIdx.x;
    const int xcd = bx & 7, idx = bx >> 3;
    const int m0 = (xcd * 8 + idx / 6) << 7;
    const int n0 = (idx % 6) << 7;
    unsigned short* oh = Gh + (long)m0 * ND + n0;
    unsigned short* ol = Gl + (long)m0 * ND + n0;
    gemm_core<3>(smem, xh + (long)m0 * ND, xl + (long)m0 * ND, ND,
                 MTh + (long)n0 * ND, MTl + (long)n0 * ND, ND, ND,
                 [=](int r, int c, float v) {
                     unsigned short hh = f2bf(v);
                     oh[(long)r * ND + c] = hh;
                     ol[(long)r * ND + c] = f2bf(v - bf2f(hh));
                 });
}

// scores[bl][s][t] = G_s . x_t + w[t]. flat grid 512; xcd = batch (x[bl]
// and G[bl] panels L2-resident per XCD); n cycles fastest within XCD.
__global__ __launch_bounds__(256, 2) void k_scores(
    const unsigned short* __restrict__ Gh, const unsigned short* __restrict__ Gl,
    const unsigned short* __restrict__ xh, const unsigned short* __restrict__ xl,
    const float* __restrict__ wv, float* __restrict__ Sc)
{
    __shared__ __align__(16) char smem[32768];
    const int bx = blockIdx.x;
    const int bl = bx & 7, idx = bx >> 3;
    const int m0 = (idx >> 3) << 7;
    const int n0 = (idx & 7) << 7;
    const long ao = ((long)bl * NS + m0) * ND;
    const long bo = ((long)bl * NS + n0) * ND;
    const float* ww = wv + bl * NS + n0;
    float* out = Sc + ((long)bl * NS + m0) * NS + n0;
    gemm_core<3>(smem, Gh + ao, Gl + ao, ND, xh + bo, xl + bo, ND, ND,
                 [=](int r, int c, float v) { out[(long)r * NS + c] = v + ww[c]; });
}

// fused: blocks [0,384) Z = x*NT_h + s_h -> ZT (xcd-banded m, NT resident);
//        blocks [384,2432) softmax in place.
__global__ __launch_bounds__(256, 2) void k_ZSM(
    const unsigned short* __restrict__ xh, const unsigned short* __restrict__ NTh,
    const float* __restrict__ sh, unsigned short* __restrict__ ZT,
    float* __restrict__ Sc)
{
    __shared__ __align__(16) char smem[16384];
    const int bx = blockIdx.x;
    if (bx < 384) {
        const int xcd = bx & 7, idx = bx >> 3;
        const int m0 = (xcd * 8 + idx / 6) << 7;
        const int n0 = (idx % 6) << 7;
        const int bl = m0 >> 10;
        const int s0 = m0 & (NS - 1);
        unsigned short* zt = ZT + (long)bl * (ND * NS);
        gemm_core<1>(smem, xh + (long)m0 * ND, nullptr, ND,
                     NTh + (long)n0 * ND, nullptr, ND, ND,
                     [=](int r, int c, float v) {
                         zt[(long)(n0 + c) * NS + s0 + r] = f2bf(v + sh[n0 + c]);
                     });
    } else {
        softmax_rows(Sc, bx - 384);
    }
}

// fused: blocks [0,384) out += P*Z (xcd = batch: P[bl]+ZT[bl] resident);
//        blocks [384,768) G(next head) = x * M_{h+1} (xcd-banded m).
template<int MODE>   // 0: first head (write + bias), 1: accumulate
__global__ __launch_bounds__(256, 2) void k_PVG(
    const unsigned short* __restrict__ P, const unsigned short* __restrict__ ZT,
    const float* __restrict__ bp, float* __restrict__ outp,
    const unsigned short* __restrict__ xh, const unsigned short* __restrict__ xl,
    const unsigned short* __restrict__ MTh, const unsigned short* __restrict__ MTl,
    unsigned short* __restrict__ Gh, unsigned short* __restrict__ Gl)
{
    __shared__ __align__(16) char smem[32768];
    const int bx = blockIdx.x;
    if (bx < 384) {
        const int bl = bx & 7, idx = bx >> 3;
        const int m0 = (idx / 6) << 7;
        const int n0 = (idx % 6) << 7;
        const unsigned short* A = P + ((long)bl * NS + m0) * (2 * NS);
        const unsigned short* B = ZT + (long)bl * (ND * NS) + (long)n0 * NS;
        float* o = outp + ((long)bl * NS + m0) * ND + n0;
        const float* bi = bp + n0;
        gemm_core<1>(smem, A, nullptr, 2 * NS, B, nullptr, NS, NS,
                     [=](int r, int c, float v) {
                         float* d = o + (long)r * ND + c;
                         if constexpr (MODE == 0) *d = v + bi[c];
                         else *d += v;
                     });
    } else {
        const int g = bx - 384;
        const int xcd = g & 7, idx = g >> 3;
        const int m0 = (xcd * 8 + idx / 6) << 7;
        const int n0 = (idx % 6) << 7;
        unsigned short* oh = Gh + (long)m0 * ND + n0;
        unsigned short* ol = Gl + (long)m0 * ND + n0;
        gemm_core<3>(smem, xh + (long)m0 * ND, xl + (long)m0 * ND, ND,
                     MTh + (long)n0 * ND, MTl + (long)n0 * ND, ND, ND,
                     [=](int r, int c, float v) {
                         unsigned short hh = f2bf(v);
                         oh[(long)r * ND + c] = hh;
                         ol[(long)r * ND + c] = f2bf(v - bf2f(hh));
                     });
    }
}

// ---------------------------------------------------------------------------

extern "C" void kernel_launch(void* const* d_in, const int* in_sizes, int n_in,
                              void* d_out, int out_size, void* d_ws, size_t ws_size,
                              hipStream_t stream) {
    (void)in_sizes; (void)n_in; (void)out_size; (void)ws_size;
    const float* x  = (const float*)d_in[0];
    const float* Wq = (const float*)d_in[1];
    const float* bq = (const float*)d_in[2];
    const float* Wk = (const float*)d_in[3];
    const float* bk = (const float*)d_in[4];  (void)bk;  // cancels in softmax
    const float* Wv = (const float*)d_in[5];
    const float* bv = (const float*)d_in[6];
    const float* Wp = (const float*)d_in[7];
    const float* bp = (const float*)d_in[8];

    const size_t nx  = (size_t)NB * NS * ND;   // 6,291,456
    const size_t nw  = (size_t)NH * ND * ND;   // 7,077,888

    char* p = (char*)d_ws;
    auto alloc = [&](size_t bytes) -> void* {
        void* r = (void*)p;
        p += (bytes + 255) & ~(size_t)255;
        return r;
    };
    // persistent
    unsigned short* xh   = (unsigned short*)alloc(nx * 2);
    unsigned short* xl   = (unsigned short*)alloc(nx * 2);
    unsigned short* MTh  = (unsigned short*)alloc(nw * 2);
    unsigned short* MTl  = (unsigned short*)alloc(nw * 2);
    unsigned short* NTb  = (unsigned short*)alloc(nw * 2);
    float*          rk   = (float*)alloc((size_t)NH * ND * 4);
    float*          s_all= (float*)alloc((size_t)NH * ND * 4);
    float*          w_all= (float*)alloc((size_t)NH * NB * NS * 4);
    // union region U: phase A = {Wq,Wk splits | Wvb,WpT}; phase B = {G,Sc,ZT}
    char* U = (char*)alloc(2 * nx * 2 + ((size_t)NB * NS * NS * 4) + ((size_t)NB * NS * ND * 2));
    // phase A views
    unsigned short* Wqh = (unsigned short*)U;
    unsigned short* Wql = Wqh + nw;
    unsigned short* Wkh = Wql + nw;
    unsigned short* Wkl = Wkh + nw;
    unsigned short* Wvb = (unsigned short*)U;        // after MT done
    unsigned short* WpT = Wvb + nw;
    // phase B views
    unsigned short* Gh = (unsigned short*)U;
    unsigned short* Gl = Gh + nx;
    float*          Sc = (float*)(Gl + nx);
    unsigned short* ZT = (unsigned short*)(Sc + (size_t)NB * NS * NS);

    // ---------------- setup (4 fused launches) ----------------
    k_setup1<<<22272, 256, 0, stream>>>(x, xh, xl, Wq, Wqh, Wql, Wk, Wkh, Wkl, bq, rk);
    k_setup2<<<2480, 256, 0, stream>>>(Wkh, Wkl, Wqh, Wql, MTh, MTl, x, rk, w_all);
    k_setup3<<<8640, 256, 0, stream>>>(Wv, Wvb, Wp, WpT);
    k_setup4<<<2736, 256, 0, stream>>>(WpT, Wvb, NTb, bv, s_all);

    // ---------------- per-head pipeline ----------------
    k_G0<<<384, 256, 0, stream>>>(xh, xl, MTh, MTl, Gh, Gl);
    for (int h = 0; h < NH; h++) {
        const long hwn = (long)(h + 1) * ND * ND;   // next head's M
        k_scores<<<512, 256, 0, stream>>>(Gh, Gl, xh, xl,
                                          w_all + (long)h * NB * NS, Sc);
        k_ZSM<<<2432, 256, 0, stream>>>(xh, NTb + (long)h * ND * ND,
                                        s_all + h * ND, ZT, Sc);
        const int ng = (h + 1 < NH) ? 768 : 384;
        if (h == 0)
            k_PVG<0><<<ng, 256, 0, stream>>>((unsigned short*)Sc, ZT, bp, (float*)d_out,
                                             xh, xl, MTh + hwn, MTl + hwn, Gh, Gl);
        else
            k_PVG<1><<<ng, 256, 0, stream>>>((unsigned short*)Sc, ZT, bp, (float*)d_out,
                                             xh, xl,
                                             MTh + ((h + 1 < NH) ? hwn : 0),
                                             MTl + ((h + 1 < NH) ? hwn : 0), Gh, Gl);
    }
}

// Round 9
// 1380.681 us; speedup vs baseline: 7.4161x; 1.0821x over previous
//
#include <hip/hip_runtime.h>

// ---------------------------------------------------------------------------
// MultiHeadAttention (full-width per-head projections), MI355X gfx950.
// Round 9: BK=64 K-tiles (half the barrier pairs per GEMM; swizzle re-derived
// for [128][64]: pc = c_log ^ (row&7), staging source c_src = (lane&7)^(lane>>3),
// same involution both sides), XCD remap on setup2/setup4 GEMM parts, and
// per-head launch rebalance (Z joins scores launch; softmax standalone).
// Sync skeleton UNCHANGED from the replay-verified R4/R7/R8 core:
// single buffer, per K-tile: sync -> stage(global_load_lds) -> sync -> ds+MFMA.
// Math unchanged:
//   scores = softmax_t( 8*( x M_h x^T + w_t ) ),  M_h = Wq_h Wk_h^T
//   out    = sum_h P_h Z_h + bp,  Z_h = x N_h + bv_h Wp_h,  N_h = Wv_h Wp_h
// 3-term bf16 hi/lo split on the score path; bf16 elsewhere; fp32 softmax.
// ---------------------------------------------------------------------------

typedef __attribute__((ext_vector_type(8))) short bf16x8;
typedef __attribute__((ext_vector_type(4))) float fx4;

#define NB 8
#define NS 1024
#define ND 768
#define NH 12

__device__ __forceinline__ unsigned short f2bf(float x) {
    unsigned int u = __float_as_uint(x);
    u += 0x7fffu + ((u >> 16) & 1u);   // round-to-nearest-even bf16
    return (unsigned short)(u >> 16);
}
__device__ __forceinline__ float bf2f(unsigned short h) {
    return __uint_as_float(((unsigned int)h) << 16);
}

// async global->LDS, 16B per lane; LDS base must be wave-uniform.
__device__ __forceinline__ void gll16(const void* g, void* l) {
    __builtin_amdgcn_global_load_lds(
        (const __attribute__((address_space(1))) void*)g,
        (__attribute__((address_space(3))) void*)l, 16, 0, 0);
}

// ---------------- elementwise bodies ----------------------------------------
__device__ __forceinline__ void split_body(const float* __restrict__ in,
                                           unsigned short* __restrict__ hi,
                                           unsigned short* __restrict__ lo, int i) {
    float4 v = ((const float4*)in)[i];
    ushort4 h, l;
    h.x = f2bf(v.x); l.x = f2bf(v.x - bf2f(h.x));
    h.y = f2bf(v.y); l.y = f2bf(v.y - bf2f(h.y));
    h.z = f2bf(v.z); l.z = f2bf(v.z - bf2f(h.z));
    h.w = f2bf(v.w); l.w = f2bf(v.w - bf2f(h.w));
    ((ushort4*)hi)[i] = h;
    ((ushort4*)lo)[i] = l;
}

// ---------------------------------------------------------------------------
// MFMA GEMM core, BK=64: 128x128 tile, 4 waves (2x2), single-buffer, per
// K-tile: __syncthreads -> stage (global_load_lds) -> __syncthreads -> ds+MFMA
// (schedule identical to the replay-verified R4/R7/R8 structure; BK is a
// parameter change). LDS tile [128 rows][64 bf16] = 16KB, row stride 128B.
// Swizzle: physical 16B-chunk pc = c_log ^ (row&7).
//   write side: row&7 == lane>>3, source chunk c_src = (lane&7)^(lane>>3),
//               LDS dest linear (wave-uniform base + lane*16).
//   read side:  row&7 == lr&7, pc = ((kk*4+lg) ^ (lr&7)).
// 8 lanes per chunk-column = ds_read_b128 floor -> no extra bank conflicts.
// C/D layout (HW-verified): col = lane&15, row = (lane>>4)*4 + reg.
// ---------------------------------------------------------------------------
template<int NTERMS, class Epi>
__device__ __forceinline__ void gemm_core(
    char* __restrict__ smem,
    const unsigned short* __restrict__ Ah, const unsigned short* __restrict__ Al, int lda,
    const unsigned short* __restrict__ Bh, const unsigned short* __restrict__ Bl, int ldb,
    int K, Epi epi)
{
    constexpr int TILE = 16384;              // bytes per [128][64] bf16 tile

    const int t = threadIdx.x;
    const int lane = t & 63;
    const int w = t >> 6;
    const int wm = (w >> 1) << 6;
    const int wn = (w & 1) << 6;
    const int lr = lane & 15;
    const int lg = lane >> 4;

    // staging geometry: wave w stages rows [w*32, w*32+32) of each tile in 4
    // instructions; instruction ii covers row w*32 + ii*8 + (lane>>3),
    // physical chunk lane&7, global source chunk (lane&7)^(lane>>3).
    const int l3 = lane >> 3;
    const int cs = (lane & 7) ^ l3;
    const int ldsw = w << 12;                // wave-uniform LDS byte offset

    const long gsA = (long)(w * 32 + l3) * lda * 2 + cs * 16;
    const long gsB = (long)(w * 32 + l3) * ldb * 2 + cs * 16;
    const long giA = (long)lda * 16;         // +8 rows, in bytes
    const long giB = (long)ldb * 16;

    const char* pAh = (const char*)Ah;
    const char* pBh = (const char*)Bh;
    const char* pAl = (const char*)Al;
    const char* pBl = (const char*)Bl;
    char* smA  = smem;
    char* smB  = smem + TILE;
    char* smA2 = smem + ((NTERMS == 3) ? 2 * TILE : 0);
    char* smB2 = smem + ((NTERMS == 3) ? 3 * TILE : TILE);

    int rowA[4], rowB[4];
    #pragma unroll
    for (int i = 0; i < 4; i++) {
        rowA[i] = (wm + (i << 4) + lr) << 6;   // ushort index of row base
        rowB[i] = (wn + (i << 4) + lr) << 6;
    }
    const int lr7 = lr & 7;

    fx4 acc[4][4] = {};

    for (int k0 = 0; k0 < K; k0 += 64) {
        const long kb2 = (long)k0 * 2;
        __syncthreads();
        #pragma unroll
        for (int ii = 0; ii < 4; ii++) {
            const int lo = ldsw + (ii << 10);
            gll16(pAh + gsA + ii * giA + kb2, smA + lo);
            gll16(pBh + gsB + ii * giB + kb2, smB + lo);
            if constexpr (NTERMS == 3) {
                gll16(pAl + gsA + ii * giA + kb2, smA2 + lo);
                gll16(pBl + gsB + ii * giB + kb2, smB2 + lo);
            }
        }
        __syncthreads();

        #pragma unroll
        for (int kk = 0; kk < 2; kk++) {
            const int pc = (((kk << 2) + lg) ^ lr7) << 3;   // ushort offset
            bf16x8 fa[4], fb[4], fa2[4], fb2[4];
            #pragma unroll
            for (int i = 0; i < 4; i++) {
                fa[i] = *(const bf16x8*)((const unsigned short*)smA + rowA[i] + pc);
                fb[i] = *(const bf16x8*)((const unsigned short*)smB + rowB[i] + pc);
            }
            if constexpr (NTERMS == 3) {
                #pragma unroll
                for (int i = 0; i < 4; i++) {
                    fa2[i] = *(const bf16x8*)((const unsigned short*)smA2 + rowA[i] + pc);
                    fb2[i] = *(const bf16x8*)((const unsigned short*)smB2 + rowB[i] + pc);
                }
            }
            #pragma unroll
            for (int i = 0; i < 4; i++)
                #pragma unroll
                for (int j = 0; j < 4; j++) {
                    acc[i][j] = __builtin_amdgcn_mfma_f32_16x16x32_bf16(fa[i], fb[j], acc[i][j], 0, 0, 0);
                    if constexpr (NTERMS == 3) {
                        acc[i][j] = __builtin_amdgcn_mfma_f32_16x16x32_bf16(fa[i], fb2[j], acc[i][j], 0, 0, 0);
                        acc[i][j] = __builtin_amdgcn_mfma_f32_16x16x32_bf16(fa2[i], fb[j], acc[i][j], 0, 0, 0);
                    }
                }
        }
    }

    #pragma unroll
    for (int i = 0; i < 4; i++)
        #pragma unroll
        for (int j = 0; j < 4; j++)
            #pragma unroll
            for (int r = 0; r < 4; r++)
                epi(wm + (i << 4) + (lg << 2) + r, wn + (j << 4) + lr, acc[i][j][r]);
}

// ---------------- softmax body (wave per row, 4 rows per block) --------------
__device__ __forceinline__ void softmax_rows(float* __restrict__ Sc, int blk) {
    int row = blk * 4 + ((int)threadIdx.x >> 6);
    int lane = threadIdx.x & 63;
    float* rp = Sc + (long)row * NS;
    const float4* src = (const float4*)rp + (lane << 2);
    float v[16];
    #pragma unroll
    for (int i = 0; i < 4; i++) {
        float4 a = src[i];
        v[i * 4 + 0] = a.x; v[i * 4 + 1] = a.y; v[i * 4 + 2] = a.z; v[i * 4 + 3] = a.w;
    }
    float m = v[0];
    #pragma unroll
    for (int i = 1; i < 16; i++) m = fmaxf(m, v[i]);
    #pragma unroll
    for (int o = 32; o > 0; o >>= 1) m = fmaxf(m, __shfl_xor(m, o));
    float s = 0.f, p[16];
    #pragma unroll
    for (int i = 0; i < 16; i++) { p[i] = __expf((v[i] - m) * 8.0f); s += p[i]; }
    #pragma unroll
    for (int o = 32; o > 0; o >>= 1) s += __shfl_xor(s, o);
    float inv = 1.0f / s;
    unsigned int wrd[8];
    #pragma unroll
    for (int i = 0; i < 8; i++) {
        unsigned int u0 = f2bf(p[2 * i] * inv);
        unsigned int u1 = f2bf(p[2 * i + 1] * inv);
        wrd[i] = u0 | (u1 << 16);
    }
    uint4* dst = (uint4*)((unsigned short*)rp + (lane << 4));
    dst[0] = make_uint4(wrd[0], wrd[1], wrd[2], wrd[3]);
    dst[1] = make_uint4(wrd[4], wrd[5], wrd[6], wrd[7]);
}

// ------------------------- fused setup kernels -------------------------------
// setup1: split x (6144) | split Wq (6912) | split Wk (6912) | rk (2304).
__global__ void k_setup1(
    const float* __restrict__ x, unsigned short* __restrict__ xh, unsigned short* __restrict__ xl,
    const float* __restrict__ Wq, unsigned short* __restrict__ Wqh, unsigned short* __restrict__ Wql,
    const float* __restrict__ Wk, unsigned short* __restrict__ Wkh, unsigned short* __restrict__ Wkl,
    const float* __restrict__ bq, float* __restrict__ rk)
{
    const int bx = blockIdx.x;
    if (bx < 6144) {
        split_body(x, xh, xl, bx * 256 + threadIdx.x);
    } else if (bx < 13056) {
        split_body(Wq, Wqh, Wql, (bx - 6144) * 256 + threadIdx.x);
    } else if (bx < 19968) {
        split_body(Wk, Wkh, Wkl, (bx - 13056) * 256 + threadIdx.x);
    } else {
        const int idx = bx - 19968;            // [0,2304)
        const int h = idx / 192;
        const int d = (idx % 192) * 4 + ((int)threadIdx.x >> 6);
        const int lane = threadIdx.x & 63;
        const float4* row = (const float4*)(Wk + ((long)h * ND + d) * ND);
        const float4* bv4 = (const float4*)(bq + h * ND);
        float acc = 0.f;
        #pragma unroll
        for (int i = 0; i < 3; i++) {
            float4 a = row[lane + (i << 6)];
            float4 b = bv4[lane + (i << 6)];
            acc += a.x * b.x + a.y * b.y + a.z * b.z + a.w * b.w;
        }
        #pragma unroll
        for (int o = 32; o > 0; o >>= 1) acc += __shfl_xor(acc, o);
        if (lane == 0) rk[h * ND + d] = acc;
    }
}

// setup2: k_MT (432, 3-term gemm, XCD-chunked) | k_w (2048).
__global__ __launch_bounds__(256, 2) void k_setup2(
    const unsigned short* __restrict__ Wkh, const unsigned short* __restrict__ Wkl,
    const unsigned short* __restrict__ Wqh, const unsigned short* __restrict__ Wql,
    unsigned short* __restrict__ MTh, unsigned short* __restrict__ MTl,
    const float* __restrict__ x, const float* __restrict__ rk, float* __restrict__ w_all)
{
    __shared__ __align__(16) char smem[65536];
    const int bx = blockIdx.x;
    if (bx < 432) {
        const int tid = (bx & 7) * 54 + (bx >> 3);   // XCD-contiguous tiles
        const int n0 = (tid % 6) << 7;
        const int m0 = ((tid / 6) % 6) << 7;
        const long hw = (long)(tid / 36) * (ND * ND);
        unsigned short* oh = MTh + hw + (long)m0 * ND + n0;
        unsigned short* ol = MTl + hw + (long)m0 * ND + n0;
        gemm_core<3>(smem, Wkh + hw + (long)m0 * ND, Wkl + hw + (long)m0 * ND, ND,
                     Wqh + hw + (long)n0 * ND, Wql + hw + (long)n0 * ND, ND, ND,
                     [=](int r, int c, float v) {
                         unsigned short hh = f2bf(v);
                         oh[r * ND + c] = hh;
                         ol[r * ND + c] = f2bf(v - bf2f(hh));
                     });
    } else {
        float* srk = (float*)smem;               // 9216 floats = 36KB
        for (int i = threadIdx.x; i < NH * ND; i += 256) srk[i] = rk[i];
        __syncthreads();
        const int row = (bx - 432) * 4 + ((int)threadIdx.x >> 6);
        const int lane = threadIdx.x & 63;
        const float4* xr = (const float4*)(x + (long)row * ND);
        float4 xa[3];
        #pragma unroll
        for (int i = 0; i < 3; i++) xa[i] = xr[lane + (i << 6)];
        for (int h = 0; h < NH; h++) {
            const float* r = srk + h * ND;
            float acc = 0.f;
            #pragma unroll
            for (int i = 0; i < 3; i++) {
                int e = (lane + (i << 6)) << 2;
                acc += xa[i].x * r[e] + xa[i].y * r[e + 1]
                     + xa[i].z * r[e + 2] + xa[i].w * r[e + 3];
            }
            #pragma unroll
            for (int o = 32; o > 0; o >>= 1) acc += __shfl_xor(acc, o);
            if (lane == 0) w_all[h * (NB * NS) + row] = acc;
        }
    }
}

// setup3 (after MT consumed Wq/Wk splits): castbf Wv (6912) | transpose Wp (1728).
__global__ void k_setup3(const float* __restrict__ Wv, unsigned short* __restrict__ Wvb,
                         const float* __restrict__ Wp, unsigned short* __restrict__ WpT)
{
    __shared__ float tile[64][65];
    const int bx = blockIdx.x;
    if (bx < 6912) {
        int i = bx * 256 + threadIdx.x;
        float4 v = ((const float4*)Wv)[i];
        ushort4 h;
        h.x = f2bf(v.x); h.y = f2bf(v.y); h.z = f2bf(v.z); h.w = f2bf(v.w);
        ((ushort4*)Wvb)[i] = h;
    } else {
        const int idx = bx - 6912;             // [0,1728)
        const int c0 = (idx % 12) * 64;
        const int r0 = ((idx / 12) % 12) * 64;
        const long zo = (long)(idx / 144) * (ND * ND);
        const float* in = Wp + zo;
        unsigned short* oh = WpT + zo;
        const int tc = threadIdx.x & 63, t4 = threadIdx.x >> 6;
        #pragma unroll
        for (int i = 0; i < 16; i++) {
            int r = (i << 2) + t4;
            tile[r][tc] = in[(long)(r0 + r) * ND + c0 + tc];
        }
        __syncthreads();
        #pragma unroll
        for (int i = 0; i < 16; i++) {
            int c = (i << 2) + t4;
            oh[(long)(c0 + c) * ND + r0 + tc] = f2bf(tile[tc][c]);
        }
    }
}

// setup4: k_NT (432, 1-term gemm, XCD-chunked) | k_sh (2304).
__global__ __launch_bounds__(256, 2) void k_setup4(
    const unsigned short* __restrict__ WpT, const unsigned short* __restrict__ Wvb,
    unsigned short* __restrict__ NTo, const float* __restrict__ bv,
    float* __restrict__ s_all)
{
    __shared__ __align__(16) char smem[32768];
    const int bx = blockIdx.x;
    if (bx < 432) {
        const int tid = (bx & 7) * 54 + (bx >> 3);   // XCD-contiguous tiles
        const int n0 = (tid % 6) << 7;
        const int m0 = ((tid / 6) % 6) << 7;
        const long hw = (long)(tid / 36) * (ND * ND);
        unsigned short* o = NTo + hw + (long)m0 * ND + n0;
        gemm_core<1>(smem, WpT + hw + (long)m0 * ND, nullptr, ND,
                     Wvb + hw + (long)n0 * ND, nullptr, ND, ND,
                     [=](int r, int c, float v) { o[r * ND + c] = f2bf(v); });
    } else {
        const int idx = bx - 432;              // [0,2304)
        const int h = idx / 192;
        const int j = (idx % 192) * 4 + ((int)threadIdx.x >> 6);
        const int lane = threadIdx.x & 63;
        const ushort4* row = (const ushort4*)(WpT + ((long)h * ND + j) * ND);
        const float* bvh = bv + h * ND;
        float acc = 0.f;
        #pragma unroll
        for (int i = 0; i < 3; i++) {
            int c = lane + (i << 6);
            ushort4 u = row[c];
            int e = c << 2;
            acc += bf2f(u.x) * bvh[e] + bf2f(u.y) * bvh[e + 1]
                 + bf2f(u.z) * bvh[e + 2] + bf2f(u.w) * bvh[e + 3];
        }
        #pragma unroll
        for (int o = 32; o > 0; o >>= 1) acc += __shfl_xor(acc, o);
        if (lane == 0) s_all[h * ND + j] = acc;
    }
}

// ------------------------- per-head kernels (XCD-remapped) -------------------

// G = x * M_h (split out), head-0 bootstrap. flat grid 384.
__global__ __launch_bounds__(256, 2) void k_G0(
    const unsigned short* __restrict__ xh, const unsigned short* __restrict__ xl,
    const unsigned short* __restrict__ MTh, const unsigned short* __restrict__ MTl,
    unsigned short* __restrict__ Gh, unsigned short* __restrict__ Gl)
{
    __shared__ __align__(16) char smem[65536];
    const int bx = blockIdx.x;
    const int xcd = bx & 7, idx = bx >> 3;
    const int m0 = (xcd * 8 + idx / 6) << 7;
    const int n0 = (idx % 6) << 7;
    unsigned short* oh = Gh + (long)m0 * ND + n0;
    unsigned short* ol = Gl + (long)m0 * ND + n0;
    gemm_core<3>(smem, xh + (long)m0 * ND, xl + (long)m0 * ND, ND,
                 MTh + (long)n0 * ND, MTl + (long)n0 * ND, ND, ND,
                 [=](int r, int c, float v) {
                     unsigned short hh = f2bf(v);
                     oh[(long)r * ND + c] = hh;
                     ol[(long)r * ND + c] = f2bf(v - bf2f(hh));
                 });
}

// fused: blocks [0,512) scores = G.x^T + w (xcd = batch);
//        blocks [512,896) Z = x*NT_h + s_h -> ZT (xcd-banded m).
__global__ __launch_bounds__(256, 2) void k_SZ(
    const unsigned short* __restrict__ Gh, const unsigned short* __restrict__ Gl,
    const unsigned short* __restrict__ xh, const unsigned short* __restrict__ xl,
    const float* __restrict__ wv, float* __restrict__ Sc,
    const unsigned short* __restrict__ NTh, const float* __restrict__ sh,
    unsigned short* __restrict__ ZT)
{
    __shared__ __align__(16) char smem[65536];
    const int bx = blockIdx.x;
    if (bx < 512) {
        const int bl = bx & 7, idx = bx >> 3;
        const int m0 = (idx >> 3) << 7;
        const int n0 = (idx & 7) << 7;
        const long ao = ((long)bl * NS + m0) * ND;
        const long bo = ((long)bl * NS + n0) * ND;
        const float* ww = wv + bl * NS + n0;
        float* out = Sc + ((long)bl * NS + m0) * NS + n0;
        gemm_core<3>(smem, Gh + ao, Gl + ao, ND, xh + bo, xl + bo, ND, ND,
                     [=](int r, int c, float v) { out[(long)r * NS + c] = v + ww[c]; });
    } else {
        const int g = bx - 512;
        const int xcd = g & 7, idx = g >> 3;
        const int m0 = (xcd * 8 + idx / 6) << 7;
        const int n0 = (idx % 6) << 7;
        const int bl = m0 >> 10;
        const int s0 = m0 & (NS - 1);
        unsigned short* zt = ZT + (long)bl * (ND * NS);
        gemm_core<1>(smem, xh + (long)m0 * ND, nullptr, ND,
                     NTh + (long)n0 * ND, nullptr, ND, ND,
                     [=](int r, int c, float v) {
                         zt[(long)(n0 + c) * NS + s0 + r] = f2bf(v + sh[n0 + c]);
                     });
    }
}

// pure softmax, in place. grid 2048 (8192 rows).
__global__ __launch_bounds__(256) void k_SM(float* __restrict__ Sc) {
    softmax_rows(Sc, blockIdx.x);
}

// fused: blocks [0,384) out += P*Z (xcd = batch);
//        blocks [384,768) G(next head) = x * M_{h+1} (xcd-banded m).
template<int MODE>   // 0: first head (write + bias), 1: accumulate
__global__ __launch_bounds__(256, 2) void k_PVG(
    const unsigned short* __restrict__ P, const unsigned short* __restrict__ ZT,
    const float* __restrict__ bp, float* __restrict__ outp,
    const unsigned short* __restrict__ xh, const unsigned short* __restrict__ xl,
    const unsigned short* __restrict__ MTh, const unsigned short* __restrict__ MTl,
    unsigned short* __restrict__ Gh, unsigned short* __restrict__ Gl)
{
    __shared__ __align__(16) char smem[65536];
    const int bx = blockIdx.x;
    if (bx < 384) {
        const int bl = bx & 7, idx = bx >> 3;
        const int m0 = (idx / 6) << 7;
        const int n0 = (idx % 6) << 7;
        const unsigned short* A = P + ((long)bl * NS + m0) * (2 * NS);
        const unsigned short* B = ZT + (long)bl * (ND * NS) + (long)n0 * NS;
        float* o = outp + ((long)bl * NS + m0) * ND + n0;
        const float* bi = bp + n0;
        gemm_core<1>(smem, A, nullptr, 2 * NS, B, nullptr, NS, NS,
                     [=](int r, int c, float v) {
                         float* d = o + (long)r * ND + c;
                         if constexpr (MODE == 0) *d = v + bi[c];
                         else *d += v;
                     });
    } else {
        const int g = bx - 384;
        const int xcd = g & 7, idx = g >> 3;
        const int m0 = (xcd * 8 + idx / 6) << 7;
        const int n0 = (idx % 6) << 7;
        unsigned short* oh = Gh + (long)m0 * ND + n0;
        unsigned short* ol = Gl + (long)m0 * ND + n0;
        gemm_core<3>(smem, xh + (long)m0 * ND, xl + (long)m0 * ND, ND,
                     MTh + (long)n0 * ND, MTl + (long)n0 * ND, ND, ND,
                     [=](int r, int c, float v) {
                         unsigned short hh = f2bf(v);
                         oh[(long)r * ND + c] = hh;
                         ol[(long)r * ND + c] = f2bf(v - bf2f(hh));
                     });
    }
}

// ---------------------------------------------------------------------------

extern "C" void kernel_launch(void* const* d_in, const int* in_sizes, int n_in,
                              void* d_out, int out_size, void* d_ws, size_t ws_size,
                              hipStream_t stream) {
    (void)in_sizes; (void)n_in; (void)out_size; (void)ws_size;
    const float* x  = (const float*)d_in[0];
    const float* Wq = (const float*)d_in[1];
    const float* bq = (const float*)d_in[2];
    const float* Wk = (const float*)d_in[3];
    const float* bk = (const float*)d_in[4];  (void)bk;  // cancels in softmax
    const float* Wv = (const float*)d_in[5];
    const float* bv = (const float*)d_in[6];
    const float* Wp = (const float*)d_in[7];
    const float* bp = (const float*)d_in[8];

    const size_t nx  = (size_t)NB * NS * ND;   // 6,291,456
    const size_t nw  = (size_t)NH * ND * ND;   // 7,077,888

    char* p = (char*)d_ws;
    auto alloc = [&](size_t bytes) -> void* {
        void* r = (void*)p;
        p += (bytes + 255) & ~(size_t)255;
        return r;
    };
    // persistent
    unsigned short* xh   = (unsigned short*)alloc(nx * 2);
    unsigned short* xl   = (unsigned short*)alloc(nx * 2);
    unsigned short* MTh  = (unsigned short*)alloc(nw * 2);
    unsigned short* MTl  = (unsigned short*)alloc(nw * 2);
    unsigned short* NTb  = (unsigned short*)alloc(nw * 2);
    float*          rk   = (float*)alloc((size_t)NH * ND * 4);
    float*          s_all= (float*)alloc((size_t)NH * ND * 4);
    float*          w_all= (float*)alloc((size_t)NH * NB * NS * 4);
    // union region U: phase A = {Wq,Wk splits | Wvb,WpT}; phase B = {G,Sc,ZT}
    char* U = (char*)alloc(2 * nx * 2 + ((size_t)NB * NS * NS * 4) + ((size_t)NB * NS * ND * 2));
    // phase A views
    unsigned short* Wqh = (unsigned short*)U;
    unsigned short* Wql = Wqh + nw;
    unsigned short* Wkh = Wql + nw;
    unsigned short* Wkl = Wkh + nw;
    unsigned short* Wvb = (unsigned short*)U;        // after MT done
    unsigned short* WpT = Wvb + nw;
    // phase B views
    unsigned short* Gh = (unsigned short*)U;
    unsigned short* Gl = Gh + nx;
    float*          Sc = (float*)(Gl + nx);
    unsigned short* ZT = (unsigned short*)(Sc + (size_t)NB * NS * NS);

    // ---------------- setup (4 fused launches) ----------------
    k_setup1<<<22272, 256, 0, stream>>>(x, xh, xl, Wq, Wqh, Wql, Wk, Wkh, Wkl, bq, rk);
    k_setup2<<<2480, 256, 0, stream>>>(Wkh, Wkl, Wqh, Wql, MTh, MTl, x, rk, w_all);
    k_setup3<<<8640, 256, 0, stream>>>(Wv, Wvb, Wp, WpT);
    k_setup4<<<2736, 256, 0, stream>>>(WpT, Wvb, NTb, bv, s_all);

    // ---------------- per-head pipeline ----------------
    k_G0<<<384, 256, 0, stream>>>(xh, xl, MTh, MTl, Gh, Gl);
    for (int h = 0; h < NH; h++) {
        const long hwn = (long)(h + 1) * ND * ND;   // next head's M
        k_SZ<<<896, 256, 0, stream>>>(Gh, Gl, xh, xl, w_all + (long)h * NB * NS,
                                      Sc, NTb + (long)h * ND * ND, s_all + h * ND, ZT);
        k_SM<<<2048, 256, 0, stream>>>(Sc);
        const int ng = (h + 1 < NH) ? 768 : 384;
        if (h == 0)
            k_PVG<0><<<ng, 256, 0, stream>>>((unsigned short*)Sc, ZT, bp, (float*)d_out,
                                             xh, xl, MTh + hwn, MTl + hwn, Gh, Gl);
        else
            k_PVG<1><<<ng, 256, 0, stream>>>((unsigned short*)Sc, ZT, bp, (float*)d_out,
                                             xh, xl,
                                             MTh + ((h + 1 < NH) ? hwn : 0),
                                             MTl + ((h + 1 < NH) ? hwn : 0), Gh, Gl);
    }
}